// Round 2
// baseline (232.903 us; speedup 1.0000x reference)
//
#include <hip/hip_runtime.h>
#include <hip/hip_fp16.h>
#include <type_traits>

#define N_NODES 100000
#define N_EDGES 1200000
#define N_FEAT 128
#define HIDDEN 64
#define N_CLASSES 40

// bucket sort parameters
#define BSHIFT 9
#define BMASK 511
#define BUCKET_NODES 512
#define NBK ((N_NODES + BUCKET_NODES - 1) / BUCKET_NODES)  // 196
#define BCAP 8192
#define CHUNK 2048

typedef _Float16 f16x8 __attribute__((ext_vector_type(8)));
typedef float f32x4 __attribute__((ext_vector_type(4)));

// ---- bucket pass: edges -> bucket-major packed array (block-aggregated writes) ----
// gcursor is zero-initialized (memset); cursors are relative, so gcursor[b] ends
// up holding bucket b's total count.

__global__ __launch_bounds__(256) void bucket_kernel(const int* __restrict__ row,
                                                     const int* __restrict__ col,
                                                     int* __restrict__ gcursor,
                                                     unsigned* __restrict__ bke, int E) {
    __shared__ int hist[NBK];
    __shared__ int pfx[NBK];
    __shared__ int gbase[NBK];
    __shared__ int lcnt[NBK];
    __shared__ unsigned ord[CHUNK];
    __shared__ unsigned char obkt[CHUNK];

    const int t = threadIdx.x;
    const int e0 = blockIdx.x * CHUNK;
    const int nE = min(CHUNK, E - e0);

    for (int i = t; i < NBK; i += 256) {
        hist[i] = 0;
        lcnt[i] = 0;
    }
    __syncthreads();

    for (int i = t; i < nE; i += 256) atomicAdd(&hist[col[e0 + i] >> BSHIFT], 1);
    __syncthreads();

    int v = (t < NBK) ? hist[t] : 0;
    if (t < NBK) pfx[t] = v;
    __syncthreads();
    for (int d = 1; d < 256; d <<= 1) {
        int add = (t >= d && t < NBK) ? pfx[t - d] : 0;
        __syncthreads();
        if (t < NBK) pfx[t] += add;
        __syncthreads();
    }
    if (t < NBK) {
        pfx[t] -= v;  // exclusive
        gbase[t] = t * BCAP + ((v > 0) ? atomicAdd(&gcursor[t], v) : 0);
    }
    __syncthreads();

    for (int i = t; i < nE; i += 256) {
        int r = row[e0 + i];
        int c = col[e0 + i];
        int b = c >> BSHIFT;
        int pos = pfx[b] + atomicAdd(&lcnt[b], 1);
        ord[pos] = ((unsigned)r << BSHIFT) | (unsigned)(c & BMASK);
        obkt[pos] = (unsigned char)b;
    }
    __syncthreads();

    for (int i = t; i < nE; i += 256) {
        int b = obkt[i];
        bke[(size_t)gbase[b] + (i - pfx[b])] = ord[i];
    }
}

// ---- fused per-bucket: bucketBase scan + hist -> rowptr + dinv -> scatter CSR ----
// Also emits gorder: a per-bucket counting sort of nodes by degree, so the
// gather kernels can put near-equal-degree nodes in the same wave (kills the
// max-of-8 degree imbalance, E[max8 Poisson(12)]/mean ~ 1.5x).

__global__ __launch_bounds__(256) void place_kernel(const int* __restrict__ gcursor,
                                                    const unsigned* __restrict__ bke,
                                                    int* __restrict__ rowptr,
                                                    float* __restrict__ dinv,
                                                    int* __restrict__ csr_src,
                                                    int* __restrict__ gorder, int n) {
    __shared__ int hist[BUCKET_NODES];
    __shared__ int cur[BUCKET_NODES];
    __shared__ int tsum[256];
    __shared__ int dh[64];
    __shared__ int dbase[64];

    const int b = blockIdx.x, t = threadIdx.x;
    const int node0 = b << BSHIFT;
    const int nNodes = min(BUCKET_NODES, n - node0);

    // bucket base: exclusive prefix over the 196 bucket counts (gcursor holds counts)
    const int myCnt = (t < NBK) ? gcursor[t] : 0;
    tsum[t] = myCnt;
    __syncthreads();
    for (int d = 1; d < 256; d <<= 1) {
        int add = (t >= d) ? tsum[t - d] : 0;
        __syncthreads();
        tsum[t] += add;
        __syncthreads();
    }
    const int base = tsum[b] - gcursor[b];  // exclusive prefix at b
    const int nb = gcursor[b];
    __syncthreads();

    hist[t] = 0;
    hist[t + 256] = 0;
    if (t < 64) dh[t] = 0;
    __syncthreads();

    const unsigned* src = bke + (size_t)b * BCAP;
    for (int i = t; i < nb; i += 256) atomicAdd(&hist[src[i] & BMASK], 1);
    __syncthreads();

    // 512-wide exclusive scan: thread t owns elements 2t, 2t+1
    const int c0 = hist[2 * t];
    const int c1 = hist[2 * t + 1];
    const int s = c0 + c1;
    tsum[t] = s;
    __syncthreads();
    for (int d = 1; d < 256; d <<= 1) {
        int add = (t >= d) ? tsum[t - d] : 0;
        __syncthreads();
        tsum[t] += add;
        __syncthreads();
    }
    const int e0 = base + tsum[t] - s;
    const int e1 = e0 + c0;

    cur[2 * t] = e0;
    cur[2 * t + 1] = e1;
    if (2 * t < nNodes) {
        rowptr[node0 + 2 * t] = e0;
        dinv[node0 + 2 * t] = rsqrtf((float)(c0 + 1));
    }
    if (2 * t + 1 < nNodes) {
        rowptr[node0 + 2 * t + 1] = e1;
        dinv[node0 + 2 * t + 1] = rsqrtf((float)(c1 + 1));
    }
    if (t == 0 && node0 + nNodes == n) rowptr[n] = N_EDGES;

    // ---- degree counting sort -> gorder (bucket-local, ascending degree) ----
    const int d0 = min(c0, 63);
    const int d1 = min(c1, 63);
    int p0 = 0, p1 = 0;
    if (2 * t < nNodes) p0 = atomicAdd(&dh[d0], 1);
    if (2 * t + 1 < nNodes) p1 = atomicAdd(&dh[d1], 1);
    __syncthreads();

    if (t < 64) tsum[t] = dh[t];
    __syncthreads();
    for (int d = 1; d < 64; d <<= 1) {
        int add = (t >= d && t < 64) ? tsum[t - d] : 0;
        __syncthreads();
        if (t < 64) tsum[t] += add;
        __syncthreads();
    }
    if (t < 64) dbase[t] = tsum[t] - dh[t];
    __syncthreads();

    if (2 * t < nNodes) gorder[node0 + dbase[d0] + p0] = node0 + 2 * t;
    if (2 * t + 1 < nNodes) gorder[node0 + dbase[d1] + p1] = node0 + 2 * t + 1;
    __syncthreads();

    for (int i = t; i < nb; i += 256) {
        unsigned p = src[i];
        int pos = atomicAdd(&cur[p & BMASK], 1);
        csr_src[pos] = (int)(p >> BSHIFT);
    }
}

// ---------------- MFMA GEMM with scaled-fp16 epilogue ----------------
// Hs[node, f<NOUT] = fp16( (X @ W)[node,f] * dinv[node] ), row stride OSTRIDE halves.
// XT = float (layer 1, cvt in-flight) or _Float16 (layer 2, native A-frags).
// v_mfma_f32_16x16x32_f16 layouts (m89/m120 verified):
//   A[m=lane&15][k=quad*8+j], B[k=quad*8+j][n=lane&15], C: col=lane&15,row=quad*4+reg.

template <typename XT, int K, int XSTRIDE, int NOUT, int NOUT_PAD, int OSTRIDE>
__global__ __launch_bounds__(256) void gemm_mfma_kernel(const XT* __restrict__ X,
                                                        const float* __restrict__ W,
                                                        const float* __restrict__ dinv,
                                                        __half* __restrict__ Hs, int M) {
    constexpr int KCH = K / 32;
    constexpr int NT = NOUT_PAD / 16;
    constexpr int WPITCH = NOUT_PAD + 2;

    __shared__ _Float16 wh[K * WPITCH];
    __shared__ float sdinv[256];

    const int tid = threadIdx.x;
    const int bnode0 = blockIdx.x * 256;

    for (int i = tid; i < K * NOUT_PAD; i += 256) {
        int k = i / NOUT_PAD, n = i % NOUT_PAD;
        wh[k * WPITCH + n] = (n < NOUT) ? (_Float16)W[k * NOUT + n] : (_Float16)0.0f;
    }
    {
        int node = bnode0 + tid;
        sdinv[tid] = (node < M) ? dinv[node] : 0.f;
    }
    __syncthreads();

    const int wid = tid >> 6;
    const int lane = tid & 63;
    const int m = lane & 15;
    const int quad = lane >> 4;

    f16x8 bf[KCH][NT];
#pragma unroll
    for (int kc = 0; kc < KCH; ++kc)
#pragma unroll
        for (int nt = 0; nt < NT; ++nt)
#pragma unroll
            for (int j = 0; j < 8; ++j)
                bf[kc][nt][j] = wh[(kc * 32 + quad * 8 + j) * WPITCH + nt * 16 + m];

    for (int nt4 = 0; nt4 < 4; ++nt4) {
        const int nb = bnode0 + wid * 64 + nt4 * 16;
        if (nb >= M) break;
        const int rowi = min(nb + m, M - 1);
        const XT* xr = X + (size_t)rowi * XSTRIDE;

        f32x4 acc[NT];
#pragma unroll
        for (int nt = 0; nt < NT; ++nt) acc[nt] = (f32x4){0.f, 0.f, 0.f, 0.f};

#pragma unroll
        for (int kc = 0; kc < KCH; ++kc) {
            f16x8 af;
            if constexpr (std::is_same<XT, float>::value) {
                float4 u0 = *(const float4*)&xr[kc * 32 + quad * 8];
                float4 u1 = *(const float4*)&xr[kc * 32 + quad * 8 + 4];
                af[0] = (_Float16)u0.x;
                af[1] = (_Float16)u0.y;
                af[2] = (_Float16)u0.z;
                af[3] = (_Float16)u0.w;
                af[4] = (_Float16)u1.x;
                af[5] = (_Float16)u1.y;
                af[6] = (_Float16)u1.z;
                af[7] = (_Float16)u1.w;
            } else {
                af = *(const f16x8*)&xr[kc * 32 + quad * 8];
            }
#pragma unroll
            for (int nt = 0; nt < NT; ++nt)
                acc[nt] = __builtin_amdgcn_mfma_f32_16x16x32_f16(af, bf[kc][nt], acc[nt], 0, 0, 0);
        }

#pragma unroll
        for (int reg = 0; reg < 4; ++reg) {
            const int node = nb + quad * 4 + reg;
            if (node < M) {
                const float s = sdinv[node - bnode0];
#pragma unroll
                for (int nt = 0; nt < NT; ++nt) {
                    const int f = nt * 16 + m;
                    if (NOUT == NOUT_PAD || f < NOUT)
                        Hs[(size_t)node * OSTRIDE + f] = __float2half(acc[nt][reg] * s);
                }
            }
        }
    }
}

// ---------------- gather: 1 wave = NG nodes, FCHUNKS-lane group per node ----------------
// g owns node gorder[wave*NG+g] (degree-sorted so groups in a wave have equal
// work), q owns a 16B feature chunk. Each lane accumulates its chunk across the
// node's whole edge list -> no cross-lane reduction, fully-coalesced self-row
// load and output store. Accumulate via v_fma_mix_f32 (f16->f32 promote exact).

__device__ inline void acc_mix16(float (&acc)[8], uint4 u, float one) {
    const unsigned* w = (const unsigned*)&u;
#pragma unroll
    for (int k = 0; k < 4; ++k) {
        asm("v_fma_mix_f32 %0, %1, %2, %0 op_sel:[0,0,0] op_sel_hi:[1,0,0]"
            : "+v"(acc[2 * k])
            : "v"(w[k]), "v"(one));
        asm("v_fma_mix_f32 %0, %1, %2, %0 op_sel:[1,0,0] op_sel_hi:[1,0,0]"
            : "+v"(acc[2 * k + 1])
            : "v"(w[k]), "v"(one));
    }
}

template <typename OutT, int NG, int FCHUNKS, int HSTRIDE, int OUTSTRIDE, bool RELU>
__global__ __launch_bounds__(256) void gather_g8_kernel(const int* __restrict__ gorder,
                                                        const int* __restrict__ rowptr,
                                                        const int* __restrict__ csr_src,
                                                        const float* __restrict__ dinv,
                                                        const __half* __restrict__ hs,
                                                        const float* __restrict__ bias,
                                                        OutT* __restrict__ out, int n) {
    const int wave = (blockIdx.x * blockDim.x + threadIdx.x) >> 6;
    const int lane = threadIdx.x & 63;
    if (NG * FCHUNKS < 64 && lane >= NG * FCHUNKS) return;
    const int g = lane / FCHUNKS;  // node slot within wave
    const int q = lane % FCHUNKS;  // 16B chunk within row
    const int idx = wave * NG + g;
    if (idx >= n) return;
    const int c = gorder[idx];

    const float one = 1.0f;
    const int eBeg = rowptr[c];
    const int eEnd = rowptr[c + 1];

    float acc[8];
#pragma unroll
    for (int j = 0; j < 8; ++j) acc[j] = 0.f;

    const __half* hq = hs + q * 8;

    // self loop
    acc_mix16(acc, *(const uint4*)(hq + (size_t)c * HSTRIDE), one);

    int e = eBeg;
    for (; e + 2 <= eEnd; e += 2) {
        int r0 = csr_src[e];
        int r1 = csr_src[e + 1];
        uint4 u0 = *(const uint4*)(hq + (size_t)r0 * HSTRIDE);
        uint4 u1 = *(const uint4*)(hq + (size_t)r1 * HSTRIDE);
        acc_mix16(acc, u0, one);
        acc_mix16(acc, u1, one);
    }
    if (e < eEnd) {
        int r = csr_src[e];
        acc_mix16(acc, *(const uint4*)(hq + (size_t)r * HSTRIDE), one);
    }

    const float dc = dinv[c];
    float o[8];
#pragma unroll
    for (int j = 0; j < 8; ++j) {
        float v = fmaf(acc[j], dc, bias[q * 8 + j]);
        o[j] = RELU ? fmaxf(v, 0.f) : v;
    }

    if constexpr (std::is_same<OutT, float>::value) {
        float* dst = &out[(size_t)c * OUTSTRIDE + q * 8];
        *(float4*)dst = make_float4(o[0], o[1], o[2], o[3]);
        *(float4*)(dst + 4) = make_float4(o[4], o[5], o[6], o[7]);
    } else {
        __half2 pk[4];
#pragma unroll
        for (int k = 0; k < 4; ++k) pk[k] = __floats2half2_rn(o[2 * k], o[2 * k + 1]);
        *(uint4*)&out[(size_t)c * OUTSTRIDE + q * 8] = *(uint4*)pk;
    }
}

// ---------------- launch ----------------

extern "C" void kernel_launch(void* const* d_in, const int* in_sizes, int n_in,
                              void* d_out, int out_size, void* d_ws, size_t ws_size,
                              hipStream_t stream) {
    const float* x = (const float*)d_in[0];
    const int* row = (const int*)d_in[1];
    const int* col = row + N_EDGES;
    const float* W1 = (const float*)d_in[2];
    const float* b1 = (const float*)d_in[3];
    const float* W2 = (const float*)d_in[4];
    const float* b2 = (const float*)d_in[5];
    float* out = (float*)d_out;

    const int N = N_NODES, E = N_EDGES;

    // 256B-aligned workspace carve-up: h1s/agg1h rows must be 128B-aligned so a
    // random 128B row spans exactly 2 cache lines (16B alignment put them at
    // 48 mod 128 -> 3 lines -> +50% gather fetch).
    char* p = (char*)d_ws;
    auto alloc = [&](size_t bytes) {
        char* q = p;
        p += (bytes + 255) & ~(size_t)255;
        return q;
    };
    int* rowptr = (int*)alloc((size_t)(N + 1) * 4);
    int* csr_src = (int*)alloc((size_t)E * 4);
    int* gcursor = (int*)alloc((size_t)NBK * 4);
    unsigned* bke = (unsigned*)alloc((size_t)NBK * BCAP * 4);
    float* dinv = (float*)alloc((size_t)N * 4);
    int* gorder = (int*)alloc((size_t)N * 4);
    __half* h1s = (__half*)alloc((size_t)N * HIDDEN * 2);     // stride 64 halves
    __half* agg1h = (__half*)alloc((size_t)N * HIDDEN * 2);   // fp16 agg, stride 64
    __half* h2s = (__half*)alloc((size_t)N * N_CLASSES * 2);  // packed stride 40 halves

    // CSR build: memset + 2 kernels
    hipMemsetAsync(gcursor, 0, (size_t)NBK * 4, stream);
    bucket_kernel<<<(E + CHUNK - 1) / CHUNK, 256, 0, stream>>>(row, col, gcursor, bke, E);
    place_kernel<<<NBK, 256, 0, stream>>>(gcursor, bke, rowptr, dinv, csr_src, gorder, N);

    // layer 1: fp32 X -> fp16 h1s (stride 64); gather -> fp16 agg1h
    gemm_mfma_kernel<float, N_FEAT, N_FEAT, HIDDEN, HIDDEN, HIDDEN>
        <<<(N + 255) / 256, 256, 0, stream>>>(x, W1, dinv, h1s, N);
    gather_g8_kernel<__half, 8, 8, HIDDEN, HIDDEN, true>
        <<<(N + 31) / 32, 256, 0, stream>>>(gorder, rowptr, csr_src, dinv, h1s, b1, agg1h, N);

    // layer 2: fp16 agg1h -> packed h2s (stride 40); gather -> fp32 out
    // 12 nodes x 5 chunks = 60/64 lanes active (vs 40/64 with 8x8 layout).
    gemm_mfma_kernel<_Float16, HIDDEN, HIDDEN, N_CLASSES, 48, N_CLASSES>
        <<<(N + 255) / 256, 256, 0, stream>>>((const _Float16*)agg1h, W2, dinv, h2s, N);
    gather_g8_kernel<float, 12, 5, N_CLASSES, N_CLASSES, false>
        <<<(N + 47) / 48, 256, 0, stream>>>(gorder, rowptr, csr_src, dinv, h2s, b2, out, N);
}

// Round 3
// 222.084 us; speedup vs baseline: 1.0487x; 1.0487x over previous
//
#include <hip/hip_runtime.h>
#include <hip/hip_fp16.h>
#include <type_traits>

#define N_NODES 100000
#define N_EDGES 1200000
#define N_FEAT 128
#define HIDDEN 64
#define N_CLASSES 40

// bucket sort parameters
#define BSHIFT 9
#define BMASK 511
#define BUCKET_NODES 512
#define NBK ((N_NODES + BUCKET_NODES - 1) / BUCKET_NODES)  // 196
#define BCAP 8192
#define CHUNK 2048

typedef _Float16 f16x8 __attribute__((ext_vector_type(8)));
typedef float f32x4 __attribute__((ext_vector_type(4)));

// ---- bucket pass: edges -> bucket-major packed array (block-aggregated writes) ----
// gcursor is zero-initialized (memset); cursors are relative, so gcursor[b] ends
// up holding bucket b's total count.

__global__ __launch_bounds__(256) void bucket_kernel(const int* __restrict__ row,
                                                     const int* __restrict__ col,
                                                     int* __restrict__ gcursor,
                                                     unsigned* __restrict__ bke, int E) {
    __shared__ int hist[NBK];
    __shared__ int pfx[NBK];
    __shared__ int gbase[NBK];
    __shared__ int lcnt[NBK];
    __shared__ unsigned ord[CHUNK];
    __shared__ unsigned char obkt[CHUNK];

    const int t = threadIdx.x;
    const int e0 = blockIdx.x * CHUNK;
    const int nE = min(CHUNK, E - e0);

    for (int i = t; i < NBK; i += 256) {
        hist[i] = 0;
        lcnt[i] = 0;
    }
    __syncthreads();

    for (int i = t; i < nE; i += 256) atomicAdd(&hist[col[e0 + i] >> BSHIFT], 1);
    __syncthreads();

    int v = (t < NBK) ? hist[t] : 0;
    if (t < NBK) pfx[t] = v;
    __syncthreads();
    for (int d = 1; d < 256; d <<= 1) {
        int add = (t >= d && t < NBK) ? pfx[t - d] : 0;
        __syncthreads();
        if (t < NBK) pfx[t] += add;
        __syncthreads();
    }
    if (t < NBK) {
        pfx[t] -= v;  // exclusive
        gbase[t] = t * BCAP + ((v > 0) ? atomicAdd(&gcursor[t], v) : 0);
    }
    __syncthreads();

    for (int i = t; i < nE; i += 256) {
        int r = row[e0 + i];
        int c = col[e0 + i];
        int b = c >> BSHIFT;
        int pos = pfx[b] + atomicAdd(&lcnt[b], 1);
        ord[pos] = ((unsigned)r << BSHIFT) | (unsigned)(c & BMASK);
        obkt[pos] = (unsigned char)b;
    }
    __syncthreads();

    for (int i = t; i < nE; i += 256) {
        int b = obkt[i];
        bke[(size_t)gbase[b] + (i - pfx[b])] = ord[i];
    }
}

// ---- fused per-bucket: bucketBase scan + hist -> rowptr + dinv -> scatter CSR ----

__global__ __launch_bounds__(256) void place_kernel(const int* __restrict__ gcursor,
                                                    const unsigned* __restrict__ bke,
                                                    int* __restrict__ rowptr,
                                                    float* __restrict__ dinv,
                                                    int* __restrict__ csr_src, int n) {
    __shared__ int hist[BUCKET_NODES];
    __shared__ int cur[BUCKET_NODES];
    __shared__ int tsum[256];

    const int b = blockIdx.x, t = threadIdx.x;
    const int node0 = b << BSHIFT;
    const int nNodes = min(BUCKET_NODES, n - node0);

    // bucket base: exclusive prefix over the 196 bucket counts (gcursor holds counts)
    const int myCnt = (t < NBK) ? gcursor[t] : 0;
    tsum[t] = myCnt;
    __syncthreads();
    for (int d = 1; d < 256; d <<= 1) {
        int add = (t >= d) ? tsum[t - d] : 0;
        __syncthreads();
        tsum[t] += add;
        __syncthreads();
    }
    const int base = tsum[b] - gcursor[b];  // exclusive prefix at b
    const int nb = gcursor[b];
    __syncthreads();

    hist[t] = 0;
    hist[t + 256] = 0;
    __syncthreads();

    const unsigned* src = bke + (size_t)b * BCAP;
    for (int i = t; i < nb; i += 256) atomicAdd(&hist[src[i] & BMASK], 1);
    __syncthreads();

    // 512-wide exclusive scan: thread t owns elements 2t, 2t+1
    const int c0 = hist[2 * t];
    const int c1 = hist[2 * t + 1];
    const int s = c0 + c1;
    tsum[t] = s;
    __syncthreads();
    for (int d = 1; d < 256; d <<= 1) {
        int add = (t >= d) ? tsum[t - d] : 0;
        __syncthreads();
        tsum[t] += add;
        __syncthreads();
    }
    const int e0 = base + tsum[t] - s;
    const int e1 = e0 + c0;

    cur[2 * t] = e0;
    cur[2 * t + 1] = e1;
    if (2 * t < nNodes) {
        rowptr[node0 + 2 * t] = e0;
        dinv[node0 + 2 * t] = rsqrtf((float)(c0 + 1));
    }
    if (2 * t + 1 < nNodes) {
        rowptr[node0 + 2 * t + 1] = e1;
        dinv[node0 + 2 * t + 1] = rsqrtf((float)(c1 + 1));
    }
    if (t == 0 && node0 + nNodes == n) rowptr[n] = N_EDGES;
    __syncthreads();

    for (int i = t; i < nb; i += 256) {
        unsigned p = src[i];
        int pos = atomicAdd(&cur[p & BMASK], 1);
        csr_src[pos] = (int)(p >> BSHIFT);
    }
}

// ---------------- MFMA GEMM with scaled-fp16 epilogue ----------------
// Hs[node, f<NOUT] = fp16( (X @ W)[node,f] * dinv[node] ), row stride OSTRIDE halves.
// XT = float (layer 1, cvt in-flight) or _Float16 (layer 2, native A-frags).
// v_mfma_f32_16x16x32_f16 layouts (m89/m120 verified):
//   A[m=lane&15][k=quad*8+j], B[k=quad*8+j][n=lane&15], C: col=lane&15,row=quad*4+reg.

template <typename XT, int K, int XSTRIDE, int NOUT, int NOUT_PAD, int OSTRIDE>
__global__ __launch_bounds__(256) void gemm_mfma_kernel(const XT* __restrict__ X,
                                                        const float* __restrict__ W,
                                                        const float* __restrict__ dinv,
                                                        __half* __restrict__ Hs, int M) {
    constexpr int KCH = K / 32;
    constexpr int NT = NOUT_PAD / 16;
    constexpr int WPITCH = NOUT_PAD + 2;

    __shared__ _Float16 wh[K * WPITCH];
    __shared__ float sdinv[256];

    const int tid = threadIdx.x;
    const int bnode0 = blockIdx.x * 256;

    for (int i = tid; i < K * NOUT_PAD; i += 256) {
        int k = i / NOUT_PAD, n = i % NOUT_PAD;
        wh[k * WPITCH + n] = (n < NOUT) ? (_Float16)W[k * NOUT + n] : (_Float16)0.0f;
    }
    {
        int node = bnode0 + tid;
        sdinv[tid] = (node < M) ? dinv[node] : 0.f;
    }
    __syncthreads();

    const int wid = tid >> 6;
    const int lane = tid & 63;
    const int m = lane & 15;
    const int quad = lane >> 4;

    f16x8 bf[KCH][NT];
#pragma unroll
    for (int kc = 0; kc < KCH; ++kc)
#pragma unroll
        for (int nt = 0; nt < NT; ++nt)
#pragma unroll
            for (int j = 0; j < 8; ++j)
                bf[kc][nt][j] = wh[(kc * 32 + quad * 8 + j) * WPITCH + nt * 16 + m];

    for (int nt4 = 0; nt4 < 4; ++nt4) {
        const int nb = bnode0 + wid * 64 + nt4 * 16;
        if (nb >= M) break;
        const int rowi = min(nb + m, M - 1);
        const XT* xr = X + (size_t)rowi * XSTRIDE;

        f32x4 acc[NT];
#pragma unroll
        for (int nt = 0; nt < NT; ++nt) acc[nt] = (f32x4){0.f, 0.f, 0.f, 0.f};

#pragma unroll
        for (int kc = 0; kc < KCH; ++kc) {
            f16x8 af;
            if constexpr (std::is_same<XT, float>::value) {
                float4 u0 = *(const float4*)&xr[kc * 32 + quad * 8];
                float4 u1 = *(const float4*)&xr[kc * 32 + quad * 8 + 4];
                af[0] = (_Float16)u0.x;
                af[1] = (_Float16)u0.y;
                af[2] = (_Float16)u0.z;
                af[3] = (_Float16)u0.w;
                af[4] = (_Float16)u1.x;
                af[5] = (_Float16)u1.y;
                af[6] = (_Float16)u1.z;
                af[7] = (_Float16)u1.w;
            } else {
                af = *(const f16x8*)&xr[kc * 32 + quad * 8];
            }
#pragma unroll
            for (int nt = 0; nt < NT; ++nt)
                acc[nt] = __builtin_amdgcn_mfma_f32_16x16x32_f16(af, bf[kc][nt], acc[nt], 0, 0, 0);
        }

#pragma unroll
        for (int reg = 0; reg < 4; ++reg) {
            const int node = nb + quad * 4 + reg;
            if (node < M) {
                const float s = sdinv[node - bnode0];
#pragma unroll
                for (int nt = 0; nt < NT; ++nt) {
                    const int f = nt * 16 + m;
                    if (NOUT == NOUT_PAD || f < NOUT)
                        Hs[(size_t)node * OSTRIDE + f] = __float2half(acc[nt][reg] * s);
                }
            }
        }
    }
}

// ---------------- gather: 1 wave = 2*NGRP nodes (strided pair per group) ----------------
// Group g (FCHUNKS lanes) owns nodes A = base+g and B = base+NGRP+g: both node
// sets contiguous across the wave -> rowptr/dinv/self-row/output accesses stay
// fully coalesced. The A/B edge loops are interleaved 2+2 so up to 4 independent
// 16B row-gather loads are in flight per group (round-1 had 2), and pair
// workload max_g(dA+dB) beats 2*max_g(d): ~11% less critical-path work.
// Per-node accumulation order (self, then edges ascending) is unchanged ->
// bitwise-identical output. Accumulate via v_fma_mix_f32 (f16->f32 exact).

__device__ inline void acc_mix16(float (&acc)[8], uint4 u, float one) {
    const unsigned* w = (const unsigned*)&u;
#pragma unroll
    for (int k = 0; k < 4; ++k) {
        asm("v_fma_mix_f32 %0, %1, %2, %0 op_sel:[0,0,0] op_sel_hi:[1,0,0]"
            : "+v"(acc[2 * k])
            : "v"(w[k]), "v"(one));
        asm("v_fma_mix_f32 %0, %1, %2, %0 op_sel:[1,0,0] op_sel_hi:[1,0,0]"
            : "+v"(acc[2 * k + 1])
            : "v"(w[k]), "v"(one));
    }
}

template <typename OutT, int NGRP, int FCHUNKS, int HSTRIDE, int OUTSTRIDE, bool RELU>
__global__ __launch_bounds__(256) void gather_pair_kernel(const int* __restrict__ rowptr,
                                                          const int* __restrict__ csr_src,
                                                          const float* __restrict__ dinv,
                                                          const __half* __restrict__ hs,
                                                          const float* __restrict__ bias,
                                                          OutT* __restrict__ out, int n) {
    const int wave = (blockIdx.x * blockDim.x + threadIdx.x) >> 6;
    const int lane = threadIdx.x & 63;
    if (NGRP * FCHUNKS < 64 && lane >= NGRP * FCHUNKS) return;
    const int g = lane / FCHUNKS;  // group (pair slot) within wave
    const int q = lane % FCHUNKS;  // 16B chunk within row
    const int base = wave * (2 * NGRP);
    const int cA = base + g;
    const int cB = base + NGRP + g;
    if (cA >= n) return;
    const bool hasB = (cB < n);

    const float one = 1.0f;
    const __half* hq = hs + q * 8;

    float accA[8], accB[8];
#pragma unroll
    for (int j = 0; j < 8; ++j) {
        accA[j] = 0.f;
        accB[j] = 0.f;
    }

    int eA = rowptr[cA];
    const int endA = rowptr[cA + 1];
    int eB = 0, endB = 0;
    if (hasB) {
        eB = rowptr[cB];
        endB = rowptr[cB + 1];
    }

    // self loops
    acc_mix16(accA, *(const uint4*)(hq + (size_t)cA * HSTRIDE), one);
    if (hasB) acc_mix16(accB, *(const uint4*)(hq + (size_t)cB * HSTRIDE), one);

    // interleaved main loop: 2 edges from each node, 4 row loads in flight
    while (eA + 2 <= endA && eB + 2 <= endB) {
        int rA0 = csr_src[eA];
        int rA1 = csr_src[eA + 1];
        int rB0 = csr_src[eB];
        int rB1 = csr_src[eB + 1];
        uint4 uA0 = *(const uint4*)(hq + (size_t)rA0 * HSTRIDE);
        uint4 uA1 = *(const uint4*)(hq + (size_t)rA1 * HSTRIDE);
        uint4 uB0 = *(const uint4*)(hq + (size_t)rB0 * HSTRIDE);
        uint4 uB1 = *(const uint4*)(hq + (size_t)rB1 * HSTRIDE);
        acc_mix16(accA, uA0, one);
        acc_mix16(accA, uA1, one);
        acc_mix16(accB, uB0, one);
        acc_mix16(accB, uB1, one);
        eA += 2;
        eB += 2;
    }
    // drain A
    for (; eA + 2 <= endA; eA += 2) {
        int r0 = csr_src[eA];
        int r1 = csr_src[eA + 1];
        uint4 u0 = *(const uint4*)(hq + (size_t)r0 * HSTRIDE);
        uint4 u1 = *(const uint4*)(hq + (size_t)r1 * HSTRIDE);
        acc_mix16(accA, u0, one);
        acc_mix16(accA, u1, one);
    }
    if (eA < endA) {
        int r = csr_src[eA];
        acc_mix16(accA, *(const uint4*)(hq + (size_t)r * HSTRIDE), one);
    }
    // drain B (endB==0 when !hasB)
    for (; eB + 2 <= endB; eB += 2) {
        int r0 = csr_src[eB];
        int r1 = csr_src[eB + 1];
        uint4 u0 = *(const uint4*)(hq + (size_t)r0 * HSTRIDE);
        uint4 u1 = *(const uint4*)(hq + (size_t)r1 * HSTRIDE);
        acc_mix16(accB, u0, one);
        acc_mix16(accB, u1, one);
    }
    if (eB < endB) {
        int r = csr_src[eB];
        acc_mix16(accB, *(const uint4*)(hq + (size_t)r * HSTRIDE), one);
    }

    // epilogue A
    {
        const float dc = dinv[cA];
        float o[8];
#pragma unroll
        for (int j = 0; j < 8; ++j) {
            float v = fmaf(accA[j], dc, bias[q * 8 + j]);
            o[j] = RELU ? fmaxf(v, 0.f) : v;
        }
        if constexpr (std::is_same<OutT, float>::value) {
            float* dst = &out[(size_t)cA * OUTSTRIDE + q * 8];
            *(float4*)dst = make_float4(o[0], o[1], o[2], o[3]);
            *(float4*)(dst + 4) = make_float4(o[4], o[5], o[6], o[7]);
        } else {
            __half2 pk[4];
#pragma unroll
            for (int k = 0; k < 4; ++k) pk[k] = __floats2half2_rn(o[2 * k], o[2 * k + 1]);
            *(uint4*)&out[(size_t)cA * OUTSTRIDE + q * 8] = *(uint4*)pk;
        }
    }
    // epilogue B
    if (hasB) {
        const float dc = dinv[cB];
        float o[8];
#pragma unroll
        for (int j = 0; j < 8; ++j) {
            float v = fmaf(accB[j], dc, bias[q * 8 + j]);
            o[j] = RELU ? fmaxf(v, 0.f) : v;
        }
        if constexpr (std::is_same<OutT, float>::value) {
            float* dst = &out[(size_t)cB * OUTSTRIDE + q * 8];
            *(float4*)dst = make_float4(o[0], o[1], o[2], o[3]);
            *(float4*)(dst + 4) = make_float4(o[4], o[5], o[6], o[7]);
        } else {
            __half2 pk[4];
#pragma unroll
            for (int k = 0; k < 4; ++k) pk[k] = __floats2half2_rn(o[2 * k], o[2 * k + 1]);
            *(uint4*)&out[(size_t)cB * OUTSTRIDE + q * 8] = *(uint4*)pk;
        }
    }
}

// ---------------- launch ----------------

extern "C" void kernel_launch(void* const* d_in, const int* in_sizes, int n_in,
                              void* d_out, int out_size, void* d_ws, size_t ws_size,
                              hipStream_t stream) {
    const float* x = (const float*)d_in[0];
    const int* row = (const int*)d_in[1];
    const int* col = row + N_EDGES;
    const float* W1 = (const float*)d_in[2];
    const float* b1 = (const float*)d_in[3];
    const float* W2 = (const float*)d_in[4];
    const float* b2 = (const float*)d_in[5];
    float* out = (float*)d_out;

    const int N = N_NODES, E = N_EDGES;

    // 256B-aligned workspace carve-up: h1s/agg1h rows must be 128B-aligned so a
    // random 128B row spans exactly 2 cache lines (16B alignment put them at
    // 48 mod 128 -> 3 lines -> +50% gather fetch).
    char* p = (char*)d_ws;
    auto alloc = [&](size_t bytes) {
        char* q = p;
        p += (bytes + 255) & ~(size_t)255;
        return q;
    };
    int* rowptr = (int*)alloc((size_t)(N + 1) * 4);
    int* csr_src = (int*)alloc((size_t)E * 4);
    int* gcursor = (int*)alloc((size_t)NBK * 4);
    unsigned* bke = (unsigned*)alloc((size_t)NBK * BCAP * 4);
    float* dinv = (float*)alloc((size_t)N * 4);
    __half* h1s = (__half*)alloc((size_t)N * HIDDEN * 2);     // stride 64 halves
    __half* agg1h = (__half*)alloc((size_t)N * HIDDEN * 2);   // fp16 agg, stride 64
    __half* h2s = (__half*)alloc((size_t)N * N_CLASSES * 2);  // packed stride 40 halves

    // CSR build: memset + 2 kernels
    hipMemsetAsync(gcursor, 0, (size_t)NBK * 4, stream);
    bucket_kernel<<<(E + CHUNK - 1) / CHUNK, 256, 0, stream>>>(row, col, gcursor, bke, E);
    place_kernel<<<NBK, 256, 0, stream>>>(gcursor, bke, rowptr, dinv, csr_src, N);

    // layer 1: fp32 X -> fp16 h1s (stride 64); gather -> fp16 agg1h
    // 8 groups x 8 chunks x 2 nodes = 16 nodes/wave, 64 nodes/block
    gemm_mfma_kernel<float, N_FEAT, N_FEAT, HIDDEN, HIDDEN, HIDDEN>
        <<<(N + 255) / 256, 256, 0, stream>>>(x, W1, dinv, h1s, N);
    gather_pair_kernel<__half, 8, 8, HIDDEN, HIDDEN, true>
        <<<(N + 63) / 64, 256, 0, stream>>>(rowptr, csr_src, dinv, h1s, b1, agg1h, N);

    // layer 2: fp16 agg1h -> packed h2s (stride 40); gather -> fp32 out
    // 12 groups x 5 chunks x 2 nodes = 24 nodes/wave, 96 nodes/block, 60/64 lanes
    gemm_mfma_kernel<_Float16, HIDDEN, HIDDEN, N_CLASSES, 48, N_CLASSES>
        <<<(N + 255) / 256, 256, 0, stream>>>((const _Float16*)agg1h, W2, dinv, h2s, N);
    gather_pair_kernel<float, 12, 5, N_CLASSES, N_CLASSES, false>
        <<<(N + 95) / 96, 256, 0, stream>>>(rowptr, csr_src, dinv, h2s, b2, out, N);
}

// Round 4
// 212.060 us; speedup vs baseline: 1.0983x; 1.0473x over previous
//
#include <hip/hip_runtime.h>
#include <hip/hip_fp16.h>
#include <type_traits>

#define N_NODES 100000
#define N_EDGES 1200000
#define N_FEAT 128
#define HIDDEN 64
#define N_CLASSES 40

// bucket sort parameters
#define BSHIFT 9
#define BMASK 511
#define BUCKET_NODES 512
#define NBK ((N_NODES + BUCKET_NODES - 1) / BUCKET_NODES)  // 196
#define BCAP 8192
#define CHUNK 2048

typedef _Float16 f16x8 __attribute__((ext_vector_type(8)));
typedef float f32x4 __attribute__((ext_vector_type(4)));

// ---- bucket pass: edges -> bucket-major packed array (block-aggregated writes) ----
// gcursor is zero-initialized (memset); cursors are relative, so gcursor[b] ends
// up holding bucket b's total count.

__global__ __launch_bounds__(256) void bucket_kernel(const int* __restrict__ row,
                                                     const int* __restrict__ col,
                                                     int* __restrict__ gcursor,
                                                     unsigned* __restrict__ bke, int E) {
    __shared__ int hist[NBK];
    __shared__ int pfx[NBK];
    __shared__ int gbase[NBK];
    __shared__ int lcnt[NBK];
    __shared__ unsigned ord[CHUNK];
    __shared__ unsigned char obkt[CHUNK];

    const int t = threadIdx.x;
    const int e0 = blockIdx.x * CHUNK;
    const int nE = min(CHUNK, E - e0);

    for (int i = t; i < NBK; i += 256) {
        hist[i] = 0;
        lcnt[i] = 0;
    }
    __syncthreads();

    for (int i = t; i < nE; i += 256) atomicAdd(&hist[col[e0 + i] >> BSHIFT], 1);
    __syncthreads();

    int v = (t < NBK) ? hist[t] : 0;
    if (t < NBK) pfx[t] = v;
    __syncthreads();
    for (int d = 1; d < 256; d <<= 1) {
        int add = (t >= d && t < NBK) ? pfx[t - d] : 0;
        __syncthreads();
        if (t < NBK) pfx[t] += add;
        __syncthreads();
    }
    if (t < NBK) {
        pfx[t] -= v;  // exclusive
        gbase[t] = t * BCAP + ((v > 0) ? atomicAdd(&gcursor[t], v) : 0);
    }
    __syncthreads();

    for (int i = t; i < nE; i += 256) {
        int r = row[e0 + i];
        int c = col[e0 + i];
        int b = c >> BSHIFT;
        int pos = pfx[b] + atomicAdd(&lcnt[b], 1);
        ord[pos] = ((unsigned)r << BSHIFT) | (unsigned)(c & BMASK);
        obkt[pos] = (unsigned char)b;
    }
    __syncthreads();

    for (int i = t; i < nE; i += 256) {
        int b = obkt[i];
        bke[(size_t)gbase[b] + (i - pfx[b])] = ord[i];
    }
}

// ---- fused per-bucket: bucketBase scan + hist -> rowptr + dinv -> scatter CSR ----

__global__ __launch_bounds__(256) void place_kernel(const int* __restrict__ gcursor,
                                                    const unsigned* __restrict__ bke,
                                                    int* __restrict__ rowptr,
                                                    float* __restrict__ dinv,
                                                    int* __restrict__ csr_src, int n) {
    __shared__ int hist[BUCKET_NODES];
    __shared__ int cur[BUCKET_NODES];
    __shared__ int tsum[256];

    const int b = blockIdx.x, t = threadIdx.x;
    const int node0 = b << BSHIFT;
    const int nNodes = min(BUCKET_NODES, n - node0);

    // bucket base: exclusive prefix over the 196 bucket counts (gcursor holds counts)
    const int myCnt = (t < NBK) ? gcursor[t] : 0;
    tsum[t] = myCnt;
    __syncthreads();
    for (int d = 1; d < 256; d <<= 1) {
        int add = (t >= d) ? tsum[t - d] : 0;
        __syncthreads();
        tsum[t] += add;
        __syncthreads();
    }
    const int base = tsum[b] - gcursor[b];  // exclusive prefix at b
    const int nb = gcursor[b];
    __syncthreads();

    hist[t] = 0;
    hist[t + 256] = 0;
    __syncthreads();

    const unsigned* src = bke + (size_t)b * BCAP;
    for (int i = t; i < nb; i += 256) atomicAdd(&hist[src[i] & BMASK], 1);
    __syncthreads();

    // 512-wide exclusive scan: thread t owns elements 2t, 2t+1
    const int c0 = hist[2 * t];
    const int c1 = hist[2 * t + 1];
    const int s = c0 + c1;
    tsum[t] = s;
    __syncthreads();
    for (int d = 1; d < 256; d <<= 1) {
        int add = (t >= d) ? tsum[t - d] : 0;
        __syncthreads();
        tsum[t] += add;
        __syncthreads();
    }
    const int e0 = base + tsum[t] - s;
    const int e1 = e0 + c0;

    cur[2 * t] = e0;
    cur[2 * t + 1] = e1;
    if (2 * t < nNodes) {
        rowptr[node0 + 2 * t] = e0;
        dinv[node0 + 2 * t] = rsqrtf((float)(c0 + 1));
    }
    if (2 * t + 1 < nNodes) {
        rowptr[node0 + 2 * t + 1] = e1;
        dinv[node0 + 2 * t + 1] = rsqrtf((float)(c1 + 1));
    }
    if (t == 0 && node0 + nNodes == n) rowptr[n] = N_EDGES;
    __syncthreads();

    for (int i = t; i < nb; i += 256) {
        unsigned p = src[i];
        int pos = atomicAdd(&cur[p & BMASK], 1);
        csr_src[pos] = (int)(p >> BSHIFT);
    }
}

// ---------------- MFMA GEMM with scaled-fp16 epilogue ----------------
// Hs[node, f<NOUT] = fp16( (X @ W)[node,f] * dinv[node] ), row stride OSTRIDE halves.
// v_mfma_f32_16x16x32_f16 layouts (m89/m120 verified):
//   A[m=lane&15][k=quad*8+j], B[k=quad*8+j][n=lane&15], C: col=lane&15,row=quad*4+reg.

template <typename XT, int K, int XSTRIDE, int NOUT, int NOUT_PAD, int OSTRIDE>
__global__ __launch_bounds__(256) void gemm_mfma_kernel(const XT* __restrict__ X,
                                                        const float* __restrict__ W,
                                                        const float* __restrict__ dinv,
                                                        __half* __restrict__ Hs, int M) {
    constexpr int KCH = K / 32;
    constexpr int NT = NOUT_PAD / 16;
    constexpr int WPITCH = NOUT_PAD + 2;

    __shared__ _Float16 wh[K * WPITCH];
    __shared__ float sdinv[256];

    const int tid = threadIdx.x;
    const int bnode0 = blockIdx.x * 256;

    for (int i = tid; i < K * NOUT_PAD; i += 256) {
        int k = i / NOUT_PAD, n = i % NOUT_PAD;
        wh[k * WPITCH + n] = (n < NOUT) ? (_Float16)W[k * NOUT + n] : (_Float16)0.0f;
    }
    {
        int node = bnode0 + tid;
        sdinv[tid] = (node < M) ? dinv[node] : 0.f;
    }
    __syncthreads();

    const int wid = tid >> 6;
    const int lane = tid & 63;
    const int m = lane & 15;
    const int quad = lane >> 4;

    f16x8 bf[KCH][NT];
#pragma unroll
    for (int kc = 0; kc < KCH; ++kc)
#pragma unroll
        for (int nt = 0; nt < NT; ++nt)
#pragma unroll
            for (int j = 0; j < 8; ++j)
                bf[kc][nt][j] = wh[(kc * 32 + quad * 8 + j) * WPITCH + nt * 16 + m];

    for (int nt4 = 0; nt4 < 4; ++nt4) {
        const int nb = bnode0 + wid * 64 + nt4 * 16;
        if (nb >= M) break;
        const int rowi = min(nb + m, M - 1);
        const XT* xr = X + (size_t)rowi * XSTRIDE;

        f32x4 acc[NT];
#pragma unroll
        for (int nt = 0; nt < NT; ++nt) acc[nt] = (f32x4){0.f, 0.f, 0.f, 0.f};

#pragma unroll
        for (int kc = 0; kc < KCH; ++kc) {
            f16x8 af;
            if constexpr (std::is_same<XT, float>::value) {
                float4 u0 = *(const float4*)&xr[kc * 32 + quad * 8];
                float4 u1 = *(const float4*)&xr[kc * 32 + quad * 8 + 4];
                af[0] = (_Float16)u0.x;
                af[1] = (_Float16)u0.y;
                af[2] = (_Float16)u0.z;
                af[3] = (_Float16)u0.w;
                af[4] = (_Float16)u1.x;
                af[5] = (_Float16)u1.y;
                af[6] = (_Float16)u1.z;
                af[7] = (_Float16)u1.w;
            } else {
                af = *(const f16x8*)&xr[kc * 32 + quad * 8];
            }
#pragma unroll
            for (int nt = 0; nt < NT; ++nt)
                acc[nt] = __builtin_amdgcn_mfma_f32_16x16x32_f16(af, bf[kc][nt], acc[nt], 0, 0, 0);
        }

#pragma unroll
        for (int reg = 0; reg < 4; ++reg) {
            const int node = nb + quad * 4 + reg;
            if (node < M) {
                const float s = sdinv[node - bnode0];
#pragma unroll
                for (int nt = 0; nt < NT; ++nt) {
                    const int f = nt * 16 + m;
                    if (NOUT == NOUT_PAD || f < NOUT)
                        Hs[(size_t)node * OSTRIDE + f] = __float2half(acc[nt][reg] * s);
                }
            }
        }
    }
}

// ---------------- gather accumulate primitive ----------------
// v_fma_mix_f32: acc += (float)h16 * 1.0f -- exact f16->f32 promote, 1 instr/feat.

__device__ inline void acc_mix16(float (&acc)[8], uint4 u, float one) {
    const unsigned* w = (const unsigned*)&u;
#pragma unroll
    for (int k = 0; k < 4; ++k) {
        asm("v_fma_mix_f32 %0, %1, %2, %0 op_sel:[0,0,0] op_sel_hi:[1,0,0]"
            : "+v"(acc[2 * k])
            : "v"(w[k]), "v"(one));
        asm("v_fma_mix_f32 %0, %1, %2, %0 op_sel:[1,0,0] op_sel_hi:[1,0,0]"
            : "+v"(acc[2 * k + 1])
            : "v"(w[k]), "v"(one));
    }
}

// ---------------- fused gather1 + GEMM2 ----------------
// Block = 256 threads, 64 nodes. Phase 1 (R1-proven gather shape): each wave
// handles 8 nodes per round x 2 rounds; group g (8 lanes) owns one node, lane q
// owns one 16B chunk; aggregate h1s rows (self + edges, v_fma_mix), apply
// dinv[c]/b1/relu, store fp16 row to LDS. Phase 2: 64x64x40 MFMA tile from LDS
// (A = agg rows, B = W2 staged fp16), epilogue h2s[node] = acc * dinv[node],
// row stride 48 halves (96B -> every 80B payload read spans exactly 2 lines).
// Deletes the 12.8MB agg1h write + 12.8MB read of the split version; math and
// rounding order identical -> bitwise-same output.

__global__ __launch_bounds__(256) void gather1_gemm2_kernel(
    const int* __restrict__ rowptr, const int* __restrict__ csr_src,
    const float* __restrict__ dinv, const __half* __restrict__ h1s,
    const float* __restrict__ b1, const float* __restrict__ W2,
    __half* __restrict__ h2s, int n) {
    constexpr int APITCH = 72;  // halves; 144B rows keep 16B alignment for b128 LDS ops
    constexpr int WPITCH = 50;

    __shared__ _Float16 agg[64 * APITCH];
    __shared__ _Float16 wh[64 * WPITCH];
    __shared__ float sdinv[64];

    const int tid = threadIdx.x;
    const int base = blockIdx.x * 64;

    // stage W2 (64x40, zero-padded to 48 cols) and this block's dinv
    for (int i = tid; i < 64 * 48; i += 256) {
        int k = i / 48, nn = i % 48;
        wh[k * WPITCH + nn] = (nn < 40) ? (_Float16)W2[k * 40 + nn] : (_Float16)0.0f;
    }
    if (tid < 64) {
        int node = base + tid;
        sdinv[tid] = (node < n) ? dinv[node] : 0.f;
    }
    __syncthreads();

    const int wid = tid >> 6;
    const int lane = tid & 63;
    const int g = lane >> 3;  // node slot within wave
    const int q = lane & 7;   // 16B chunk within 128B row
    const float one = 1.0f;
    const __half* hq = h1s + q * 8;

    // ---- phase 1: gather 64 nodes into LDS (2 rounds of 8 nodes/wave) ----
#pragma unroll
    for (int t = 0; t < 2; ++t) {
        const int nl = t * 32 + wid * 8 + g;
        const int c = base + nl;
        if (c < n) {
            float acc[8];
#pragma unroll
            for (int j = 0; j < 8; ++j) acc[j] = 0.f;

            // self loop
            acc_mix16(acc, *(const uint4*)(hq + (size_t)c * HIDDEN), one);

            int e = rowptr[c];
            const int eEnd = rowptr[c + 1];
            for (; e + 2 <= eEnd; e += 2) {
                int r0 = csr_src[e];
                int r1 = csr_src[e + 1];
                uint4 u0 = *(const uint4*)(hq + (size_t)r0 * HIDDEN);
                uint4 u1 = *(const uint4*)(hq + (size_t)r1 * HIDDEN);
                acc_mix16(acc, u0, one);
                acc_mix16(acc, u1, one);
            }
            if (e < eEnd) {
                int r = csr_src[e];
                acc_mix16(acc, *(const uint4*)(hq + (size_t)r * HIDDEN), one);
            }

            const float dc = sdinv[nl];
            _Float16 hv[8];
#pragma unroll
            for (int j = 0; j < 8; ++j) {
                float v = fmaf(acc[j], dc, b1[q * 8 + j]);
                hv[j] = (_Float16)fmaxf(v, 0.f);
            }
            *(f16x8*)&agg[nl * APITCH + q * 8] = *(f16x8*)hv;
        }
    }
    __syncthreads();

    // ---- phase 2: GEMM2 on the 64 LDS rows ----
    const int m = lane & 15;
    const int quad = lane >> 4;

    f16x8 bf[2][3];
#pragma unroll
    for (int kc = 0; kc < 2; ++kc)
#pragma unroll
        for (int nt = 0; nt < 3; ++nt)
#pragma unroll
            for (int j = 0; j < 8; ++j)
                bf[kc][nt][j] = wh[(kc * 32 + quad * 8 + j) * WPITCH + nt * 16 + m];

    const int nl0 = wid * 16;  // this wave's 16-node tile

    f32x4 acc2[3];
#pragma unroll
    for (int nt = 0; nt < 3; ++nt) acc2[nt] = (f32x4){0.f, 0.f, 0.f, 0.f};

#pragma unroll
    for (int kc = 0; kc < 2; ++kc) {
        f16x8 af = *(const f16x8*)&agg[(nl0 + m) * APITCH + kc * 32 + quad * 8];
#pragma unroll
        for (int nt = 0; nt < 3; ++nt)
            acc2[nt] = __builtin_amdgcn_mfma_f32_16x16x32_f16(af, bf[kc][nt], acc2[nt], 0, 0, 0);
    }

#pragma unroll
    for (int reg = 0; reg < 4; ++reg) {
        const int nl = nl0 + quad * 4 + reg;
        const int node = base + nl;
        if (node < n) {
            const float s = sdinv[nl];
#pragma unroll
            for (int nt = 0; nt < 3; ++nt) {
                const int f = nt * 16 + m;
                if (f < N_CLASSES)
                    h2s[(size_t)node * 48 + f] = __float2half(acc2[nt][reg] * s);
            }
        }
    }
}

// ---------------- gather: 1 wave = NG nodes, FCHUNKS-lane group per node ----------------
// Contiguous node blocks (NO degree reordering -- R2 showed locality >> balance).
// Group g owns node wave*NG+g, lane q owns one 16B chunk; 2-deep edge unroll.

template <typename OutT, int NG, int FCHUNKS, int HSTRIDE, int OUTSTRIDE, bool RELU>
__global__ __launch_bounds__(256) void gather_kernel(const int* __restrict__ rowptr,
                                                     const int* __restrict__ csr_src,
                                                     const float* __restrict__ dinv,
                                                     const __half* __restrict__ hs,
                                                     const float* __restrict__ bias,
                                                     OutT* __restrict__ out, int n) {
    const int wave = (blockIdx.x * blockDim.x + threadIdx.x) >> 6;
    const int lane = threadIdx.x & 63;
    if (NG * FCHUNKS < 64 && lane >= NG * FCHUNKS) return;
    const int g = lane / FCHUNKS;  // node slot within wave
    const int q = lane % FCHUNKS;  // 16B chunk within row
    const int c = wave * NG + g;
    if (c >= n) return;

    const float one = 1.0f;
    const int eBeg = rowptr[c];
    const int eEnd = rowptr[c + 1];

    float acc[8];
#pragma unroll
    for (int j = 0; j < 8; ++j) acc[j] = 0.f;

    const __half* hq = hs + q * 8;

    // self loop
    acc_mix16(acc, *(const uint4*)(hq + (size_t)c * HSTRIDE), one);

    int e = eBeg;
    for (; e + 2 <= eEnd; e += 2) {
        int r0 = csr_src[e];
        int r1 = csr_src[e + 1];
        uint4 u0 = *(const uint4*)(hq + (size_t)r0 * HSTRIDE);
        uint4 u1 = *(const uint4*)(hq + (size_t)r1 * HSTRIDE);
        acc_mix16(acc, u0, one);
        acc_mix16(acc, u1, one);
    }
    if (e < eEnd) {
        int r = csr_src[e];
        acc_mix16(acc, *(const uint4*)(hq + (size_t)r * HSTRIDE), one);
    }

    const float dc = dinv[c];
    float o[8];
#pragma unroll
    for (int j = 0; j < 8; ++j) {
        float v = fmaf(acc[j], dc, bias[q * 8 + j]);
        o[j] = RELU ? fmaxf(v, 0.f) : v;
    }

    if constexpr (std::is_same<OutT, float>::value) {
        float* dst = &out[(size_t)c * OUTSTRIDE + q * 8];
        *(float4*)dst = make_float4(o[0], o[1], o[2], o[3]);
        *(float4*)(dst + 4) = make_float4(o[4], o[5], o[6], o[7]);
    } else {
        __half2 pk[4];
#pragma unroll
        for (int k = 0; k < 4; ++k) pk[k] = __floats2half2_rn(o[2 * k], o[2 * k + 1]);
        *(uint4*)&out[(size_t)c * OUTSTRIDE + q * 8] = *(uint4*)pk;
    }
}

// ---------------- launch ----------------

extern "C" void kernel_launch(void* const* d_in, const int* in_sizes, int n_in,
                              void* d_out, int out_size, void* d_ws, size_t ws_size,
                              hipStream_t stream) {
    const float* x = (const float*)d_in[0];
    const int* row = (const int*)d_in[1];
    const int* col = row + N_EDGES;
    const float* W1 = (const float*)d_in[2];
    const float* b1 = (const float*)d_in[3];
    const float* W2 = (const float*)d_in[4];
    const float* b2 = (const float*)d_in[5];
    float* out = (float*)d_out;

    const int N = N_NODES, E = N_EDGES;

    // 256B-aligned workspace carve-up: h1s/h2s rows must stay 128B/96B aligned so
    // a random row spans the minimum number of cache lines.
    char* p = (char*)d_ws;
    auto alloc = [&](size_t bytes) {
        char* q = p;
        p += (bytes + 255) & ~(size_t)255;
        return q;
    };
    int* rowptr = (int*)alloc((size_t)(N + 1) * 4);
    int* csr_src = (int*)alloc((size_t)E * 4);
    int* gcursor = (int*)alloc((size_t)NBK * 4);
    unsigned* bke = (unsigned*)alloc((size_t)NBK * BCAP * 4);
    float* dinv = (float*)alloc((size_t)N * 4);
    __half* h1s = (__half*)alloc((size_t)N * HIDDEN * 2);  // stride 64 halves (128B)
    __half* h2s = (__half*)alloc((size_t)N * 48 * 2);      // stride 48 halves (96B)

    // CSR build: memset + 2 kernels
    hipMemsetAsync(gcursor, 0, (size_t)NBK * 4, stream);
    bucket_kernel<<<(E + CHUNK - 1) / CHUNK, 256, 0, stream>>>(row, col, gcursor, bke, E);
    place_kernel<<<NBK, 256, 0, stream>>>(gcursor, bke, rowptr, dinv, csr_src, N);

    // layer 1 transform: fp32 X -> fp16 h1s (stride 64)
    gemm_mfma_kernel<float, N_FEAT, N_FEAT, HIDDEN, HIDDEN, HIDDEN>
        <<<(N + 255) / 256, 256, 0, stream>>>(x, W1, dinv, h1s, N);

    // fused: gather layer-1 (relu, b1) -> LDS -> GEMM2 -> h2s (stride 48)
    gather1_gemm2_kernel<<<(N + 63) / 64, 256, 0, stream>>>(rowptr, csr_src, dinv, h1s,
                                                            b1, W2, h2s, N);

    // layer-2 gather: 12 nodes x 5 chunks = 60/64 lanes, contiguous nodes
    gather_kernel<float, 12, 5, 48, N_CLASSES, false>
        <<<(N + 47) / 48, 256, 0, stream>>>(rowptr, csr_src, dinv, h2s, b2, out, N);
}

// Round 5
// 208.874 us; speedup vs baseline: 1.1150x; 1.0153x over previous
//
#include <hip/hip_runtime.h>
#include <hip/hip_fp16.h>
#include <type_traits>

#define N_NODES 100000
#define N_EDGES 1200000
#define N_FEAT 128
#define HIDDEN 64
#define N_CLASSES 40

// bucket sort parameters
#define BSHIFT 9
#define BMASK 511
#define BUCKET_NODES 512
#define NBK ((N_NODES + BUCKET_NODES - 1) / BUCKET_NODES)  // 196
#define BCAP 8192
#define CHUNK 2048

typedef _Float16 f16x8 __attribute__((ext_vector_type(8)));
typedef float f32x4 __attribute__((ext_vector_type(4)));

// ---- bucket pass: edges -> bucket-major packed array (block-aggregated writes) ----
// gcursor is zero-initialized (memset); cursors are relative, so gcursor[b] ends
// up holding bucket b's total count.

__global__ __launch_bounds__(256) void bucket_kernel(const int* __restrict__ row,
                                                     const int* __restrict__ col,
                                                     int* __restrict__ gcursor,
                                                     unsigned* __restrict__ bke, int E) {
    __shared__ int hist[NBK];
    __shared__ int pfx[NBK];
    __shared__ int gbase[NBK];
    __shared__ int lcnt[NBK];
    __shared__ unsigned ord[CHUNK];
    __shared__ unsigned char obkt[CHUNK];

    const int t = threadIdx.x;
    const int e0 = blockIdx.x * CHUNK;
    const int nE = min(CHUNK, E - e0);

    for (int i = t; i < NBK; i += 256) {
        hist[i] = 0;
        lcnt[i] = 0;
    }
    __syncthreads();

    for (int i = t; i < nE; i += 256) atomicAdd(&hist[col[e0 + i] >> BSHIFT], 1);
    __syncthreads();

    int v = (t < NBK) ? hist[t] : 0;
    if (t < NBK) pfx[t] = v;
    __syncthreads();
    for (int d = 1; d < 256; d <<= 1) {
        int add = (t >= d && t < NBK) ? pfx[t - d] : 0;
        __syncthreads();
        if (t < NBK) pfx[t] += add;
        __syncthreads();
    }
    if (t < NBK) {
        pfx[t] -= v;  // exclusive
        gbase[t] = t * BCAP + ((v > 0) ? atomicAdd(&gcursor[t], v) : 0);
    }
    __syncthreads();

    for (int i = t; i < nE; i += 256) {
        int r = row[e0 + i];
        int c = col[e0 + i];
        int b = c >> BSHIFT;
        int pos = pfx[b] + atomicAdd(&lcnt[b], 1);
        ord[pos] = ((unsigned)r << BSHIFT) | (unsigned)(c & BMASK);
        obkt[pos] = (unsigned char)b;
    }
    __syncthreads();

    for (int i = t; i < nE; i += 256) {
        int b = obkt[i];
        bke[(size_t)gbase[b] + (i - pfx[b])] = ord[i];
    }
}

// ---- fused per-bucket: bucketBase scan + hist -> rowptr + dinv -> scatter CSR ----

__global__ __launch_bounds__(256) void place_kernel(const int* __restrict__ gcursor,
                                                    const unsigned* __restrict__ bke,
                                                    int* __restrict__ rowptr,
                                                    float* __restrict__ dinv,
                                                    int* __restrict__ csr_src, int n) {
    __shared__ int hist[BUCKET_NODES];
    __shared__ int cur[BUCKET_NODES];
    __shared__ int tsum[256];

    const int b = blockIdx.x, t = threadIdx.x;
    const int node0 = b << BSHIFT;
    const int nNodes = min(BUCKET_NODES, n - node0);

    // bucket base: exclusive prefix over the 196 bucket counts (gcursor holds counts)
    const int myCnt = (t < NBK) ? gcursor[t] : 0;
    tsum[t] = myCnt;
    __syncthreads();
    for (int d = 1; d < 256; d <<= 1) {
        int add = (t >= d) ? tsum[t - d] : 0;
        __syncthreads();
        tsum[t] += add;
        __syncthreads();
    }
    const int base = tsum[b] - gcursor[b];  // exclusive prefix at b
    const int nb = gcursor[b];
    __syncthreads();

    hist[t] = 0;
    hist[t + 256] = 0;
    __syncthreads();

    const unsigned* src = bke + (size_t)b * BCAP;
    for (int i = t; i < nb; i += 256) atomicAdd(&hist[src[i] & BMASK], 1);
    __syncthreads();

    // 512-wide exclusive scan: thread t owns elements 2t, 2t+1
    const int c0 = hist[2 * t];
    const int c1 = hist[2 * t + 1];
    const int s = c0 + c1;
    tsum[t] = s;
    __syncthreads();
    for (int d = 1; d < 256; d <<= 1) {
        int add = (t >= d) ? tsum[t - d] : 0;
        __syncthreads();
        tsum[t] += add;
        __syncthreads();
    }
    const int e0 = base + tsum[t] - s;
    const int e1 = e0 + c0;

    cur[2 * t] = e0;
    cur[2 * t + 1] = e1;
    if (2 * t < nNodes) {
        rowptr[node0 + 2 * t] = e0;
        dinv[node0 + 2 * t] = rsqrtf((float)(c0 + 1));
    }
    if (2 * t + 1 < nNodes) {
        rowptr[node0 + 2 * t + 1] = e1;
        dinv[node0 + 2 * t + 1] = rsqrtf((float)(c1 + 1));
    }
    if (t == 0 && node0 + nNodes == n) rowptr[n] = N_EDGES;
    __syncthreads();

    for (int i = t; i < nb; i += 256) {
        unsigned p = src[i];
        int pos = atomicAdd(&cur[p & BMASK], 1);
        csr_src[pos] = (int)(p >> BSHIFT);
    }
}

// ---------------- MFMA GEMM with scaled-fp16 epilogue ----------------
// Hs[node, f<NOUT] = fp16( (X @ W)[node,f] * dinv[node] ), row stride OSTRIDE halves.
// v_mfma_f32_16x16x32_f16 layouts (m89/m120 verified):
//   A[m=lane&15][k=quad*8+j], B[k=quad*8+j][n=lane&15], C: col=lane&15,row=quad*4+reg.

template <typename XT, int K, int XSTRIDE, int NOUT, int NOUT_PAD, int OSTRIDE>
__global__ __launch_bounds__(256) void gemm_mfma_kernel(const XT* __restrict__ X,
                                                        const float* __restrict__ W,
                                                        const float* __restrict__ dinv,
                                                        __half* __restrict__ Hs, int M) {
    constexpr int KCH = K / 32;
    constexpr int NT = NOUT_PAD / 16;
    constexpr int WPITCH = NOUT_PAD + 2;

    __shared__ _Float16 wh[K * WPITCH];
    __shared__ float sdinv[256];

    const int tid = threadIdx.x;
    const int bnode0 = blockIdx.x * 256;

    for (int i = tid; i < K * NOUT_PAD; i += 256) {
        int k = i / NOUT_PAD, n = i % NOUT_PAD;
        wh[k * WPITCH + n] = (n < NOUT) ? (_Float16)W[k * NOUT + n] : (_Float16)0.0f;
    }
    {
        int node = bnode0 + tid;
        sdinv[tid] = (node < M) ? dinv[node] : 0.f;
    }
    __syncthreads();

    const int wid = tid >> 6;
    const int lane = tid & 63;
    const int m = lane & 15;
    const int quad = lane >> 4;

    f16x8 bf[KCH][NT];
#pragma unroll
    for (int kc = 0; kc < KCH; ++kc)
#pragma unroll
        for (int nt = 0; nt < NT; ++nt)
#pragma unroll
            for (int j = 0; j < 8; ++j)
                bf[kc][nt][j] = wh[(kc * 32 + quad * 8 + j) * WPITCH + nt * 16 + m];

    for (int nt4 = 0; nt4 < 4; ++nt4) {
        const int nb = bnode0 + wid * 64 + nt4 * 16;
        if (nb >= M) break;
        const int rowi = min(nb + m, M - 1);
        const XT* xr = X + (size_t)rowi * XSTRIDE;

        f32x4 acc[NT];
#pragma unroll
        for (int nt = 0; nt < NT; ++nt) acc[nt] = (f32x4){0.f, 0.f, 0.f, 0.f};

#pragma unroll
        for (int kc = 0; kc < KCH; ++kc) {
            f16x8 af;
            if constexpr (std::is_same<XT, float>::value) {
                float4 u0 = *(const float4*)&xr[kc * 32 + quad * 8];
                float4 u1 = *(const float4*)&xr[kc * 32 + quad * 8 + 4];
                af[0] = (_Float16)u0.x;
                af[1] = (_Float16)u0.y;
                af[2] = (_Float16)u0.z;
                af[3] = (_Float16)u0.w;
                af[4] = (_Float16)u1.x;
                af[5] = (_Float16)u1.y;
                af[6] = (_Float16)u1.z;
                af[7] = (_Float16)u1.w;
            } else {
                af = *(const f16x8*)&xr[kc * 32 + quad * 8];
            }
#pragma unroll
            for (int nt = 0; nt < NT; ++nt)
                acc[nt] = __builtin_amdgcn_mfma_f32_16x16x32_f16(af, bf[kc][nt], acc[nt], 0, 0, 0);
        }

#pragma unroll
        for (int reg = 0; reg < 4; ++reg) {
            const int node = nb + quad * 4 + reg;
            if (node < M) {
                const float s = sdinv[node - bnode0];
#pragma unroll
                for (int nt = 0; nt < NT; ++nt) {
                    const int f = nt * 16 + m;
                    if (NOUT == NOUT_PAD || f < NOUT)
                        Hs[(size_t)node * OSTRIDE + f] = __float2half(acc[nt][reg] * s);
                }
            }
        }
    }
}

// ---------------- gather accumulate primitive ----------------
// v_fma_mix_f32: acc += (float)h16 * 1.0f -- exact f16->f32 promote, 1 instr/feat.

__device__ inline void acc_mix16(float (&acc)[8], uint4 u, float one) {
    const unsigned* w = (const unsigned*)&u;
#pragma unroll
    for (int k = 0; k < 4; ++k) {
        asm("v_fma_mix_f32 %0, %1, %2, %0 op_sel:[0,0,0] op_sel_hi:[1,0,0]"
            : "+v"(acc[2 * k])
            : "v"(w[k]), "v"(one));
        asm("v_fma_mix_f32 %0, %1, %2, %0 op_sel:[1,0,0] op_sel_hi:[1,0,0]"
            : "+v"(acc[2 * k + 1])
            : "v"(w[k]), "v"(one));
    }
}

// ---------------- fused gather1 + GEMM2 ----------------
// Block = 256 threads, 64 nodes. Phase 1 (R1-proven gather shape): each wave
// handles 8 nodes per round x 2 rounds; group g (8 lanes) owns one node, lane q
// owns one 16B chunk; aggregate h1s rows (self + edges, v_fma_mix), apply
// dinv[c]/b1/relu, store fp16 row to LDS. Phase 2: 64x64x40 MFMA tile from LDS
// (A = agg rows, B = W2 staged fp16), epilogue writes SPLIT h2: classes 0-31 to
// h2a (64B rows, exactly 1 cache line per edge read) and classes 32-39 to h2b
// (16B rows, whole array 1.6MB -> per-XCD L2 resident). Same values, same
// roundings as the monolithic h2s -> bitwise-identical final output.

__global__ __launch_bounds__(256) void gather1_gemm2_kernel(
    const int* __restrict__ rowptr, const int* __restrict__ csr_src,
    const float* __restrict__ dinv, const __half* __restrict__ h1s,
    const float* __restrict__ b1, const float* __restrict__ W2,
    __half* __restrict__ h2a, __half* __restrict__ h2b, int n) {
    constexpr int APITCH = 72;  // halves; 144B rows keep 16B alignment for b128 LDS ops
    constexpr int WPITCH = 50;

    __shared__ _Float16 agg[64 * APITCH];
    __shared__ _Float16 wh[64 * WPITCH];
    __shared__ float sdinv[64];

    const int tid = threadIdx.x;
    const int base = blockIdx.x * 64;

    // stage W2 (64x40, zero-padded to 48 cols) and this block's dinv
    for (int i = tid; i < 64 * 48; i += 256) {
        int k = i / 48, nn = i % 48;
        wh[k * WPITCH + nn] = (nn < 40) ? (_Float16)W2[k * 40 + nn] : (_Float16)0.0f;
    }
    if (tid < 64) {
        int node = base + tid;
        sdinv[tid] = (node < n) ? dinv[node] : 0.f;
    }
    __syncthreads();

    const int wid = tid >> 6;
    const int lane = tid & 63;
    const int g = lane >> 3;  // node slot within wave
    const int q = lane & 7;   // 16B chunk within 128B row
    const float one = 1.0f;
    const __half* hq = h1s + q * 8;

    // ---- phase 1: gather 64 nodes into LDS (2 rounds of 8 nodes/wave) ----
#pragma unroll
    for (int t = 0; t < 2; ++t) {
        const int nl = t * 32 + wid * 8 + g;
        const int c = base + nl;
        if (c < n) {
            float acc[8];
#pragma unroll
            for (int j = 0; j < 8; ++j) acc[j] = 0.f;

            // self loop
            acc_mix16(acc, *(const uint4*)(hq + (size_t)c * HIDDEN), one);

            int e = rowptr[c];
            const int eEnd = rowptr[c + 1];
            for (; e + 2 <= eEnd; e += 2) {
                int r0 = csr_src[e];
                int r1 = csr_src[e + 1];
                uint4 u0 = *(const uint4*)(hq + (size_t)r0 * HIDDEN);
                uint4 u1 = *(const uint4*)(hq + (size_t)r1 * HIDDEN);
                acc_mix16(acc, u0, one);
                acc_mix16(acc, u1, one);
            }
            if (e < eEnd) {
                int r = csr_src[e];
                acc_mix16(acc, *(const uint4*)(hq + (size_t)r * HIDDEN), one);
            }

            const float dc = sdinv[nl];
            _Float16 hv[8];
#pragma unroll
            for (int j = 0; j < 8; ++j) {
                float v = fmaf(acc[j], dc, b1[q * 8 + j]);
                hv[j] = (_Float16)fmaxf(v, 0.f);
            }
            *(f16x8*)&agg[nl * APITCH + q * 8] = *(f16x8*)hv;
        }
    }
    __syncthreads();

    // ---- phase 2: GEMM2 on the 64 LDS rows ----
    const int m = lane & 15;
    const int quad = lane >> 4;

    f16x8 bf[2][3];
#pragma unroll
    for (int kc = 0; kc < 2; ++kc)
#pragma unroll
        for (int nt = 0; nt < 3; ++nt)
#pragma unroll
            for (int j = 0; j < 8; ++j)
                bf[kc][nt][j] = wh[(kc * 32 + quad * 8 + j) * WPITCH + nt * 16 + m];

    const int nl0 = wid * 16;  // this wave's 16-node tile

    f32x4 acc2[3];
#pragma unroll
    for (int nt = 0; nt < 3; ++nt) acc2[nt] = (f32x4){0.f, 0.f, 0.f, 0.f};

#pragma unroll
    for (int kc = 0; kc < 2; ++kc) {
        f16x8 af = *(const f16x8*)&agg[(nl0 + m) * APITCH + kc * 32 + quad * 8];
#pragma unroll
        for (int nt = 0; nt < 3; ++nt)
            acc2[nt] = __builtin_amdgcn_mfma_f32_16x16x32_f16(af, bf[kc][nt], acc2[nt], 0, 0, 0);
    }

#pragma unroll
    for (int reg = 0; reg < 4; ++reg) {
        const int nl = nl0 + quad * 4 + reg;
        const int node = base + nl;
        if (node < n) {
            const float s = sdinv[nl];
#pragma unroll
            for (int nt = 0; nt < 3; ++nt) {
                const int f = nt * 16 + m;
                const __half hv = __float2half(acc2[nt][reg] * s);
                if (f < 32)
                    h2a[(size_t)node * 32 + f] = hv;
                else if (f < N_CLASSES)
                    h2b[(size_t)node * 8 + (f - 32)] = hv;
            }
        }
    }
}

// ---------------- layer-2 gather: 12 nodes x 5 chunks, split h2a/h2b ----------------
// Contiguous node blocks (R2 showed locality >> balance). q<4 lanes read 16B
// chunks of h2a (stride 32 halves, 1 line/row); q==4 reads h2b (stride 8,
// L2-resident). Same accumulation order as before -> bitwise-identical.

__global__ __launch_bounds__(256) void gather2_kernel(const int* __restrict__ rowptr,
                                                      const int* __restrict__ csr_src,
                                                      const float* __restrict__ dinv,
                                                      const __half* __restrict__ h2a,
                                                      const __half* __restrict__ h2b,
                                                      const float* __restrict__ bias,
                                                      float* __restrict__ out, int n) {
    const int wave = (blockIdx.x * blockDim.x + threadIdx.x) >> 6;
    const int lane = threadIdx.x & 63;
    if (lane >= 60) return;
    const int g = lane / 5;  // node slot within wave
    const int q = lane % 5;  // feature chunk
    const int c = wave * 12 + g;
    if (c >= n) return;

    const float one = 1.0f;
    const __half* hq = (q < 4) ? (h2a + q * 8) : h2b;
    const int sh = (q < 4) ? 5 : 3;  // log2(row stride in halves)

    const int eBeg = rowptr[c];
    const int eEnd = rowptr[c + 1];

    float acc[8];
#pragma unroll
    for (int j = 0; j < 8; ++j) acc[j] = 0.f;

    // self loop
    acc_mix16(acc, *(const uint4*)(hq + ((size_t)c << sh)), one);

    int e = eBeg;
    for (; e + 2 <= eEnd; e += 2) {
        int r0 = csr_src[e];
        int r1 = csr_src[e + 1];
        uint4 u0 = *(const uint4*)(hq + ((size_t)r0 << sh));
        uint4 u1 = *(const uint4*)(hq + ((size_t)r1 << sh));
        acc_mix16(acc, u0, one);
        acc_mix16(acc, u1, one);
    }
    if (e < eEnd) {
        int r = csr_src[e];
        acc_mix16(acc, *(const uint4*)(hq + ((size_t)r << sh)), one);
    }

    const float dc = dinv[c];
    float o[8];
#pragma unroll
    for (int j = 0; j < 8; ++j) {
        float v = fmaf(acc[j], dc, bias[q * 8 + j]);
        o[j] = v;
    }

    float* dst = &out[(size_t)c * N_CLASSES + q * 8];
    *(float4*)dst = make_float4(o[0], o[1], o[2], o[3]);
    *(float4*)(dst + 4) = make_float4(o[4], o[5], o[6], o[7]);
}

// ---------------- launch ----------------

extern "C" void kernel_launch(void* const* d_in, const int* in_sizes, int n_in,
                              void* d_out, int out_size, void* d_ws, size_t ws_size,
                              hipStream_t stream) {
    const float* x = (const float*)d_in[0];
    const int* row = (const int*)d_in[1];
    const int* col = row + N_EDGES;
    const float* W1 = (const float*)d_in[2];
    const float* b1 = (const float*)d_in[3];
    const float* W2 = (const float*)d_in[4];
    const float* b2 = (const float*)d_in[5];
    float* out = (float*)d_out;

    const int N = N_NODES, E = N_EDGES;

    // 256B-aligned workspace carve-up: h1s rows 128B-aligned (2 lines/row),
    // h2a rows 64B-aligned (exactly 1 line/row), h2b 16B rows.
    char* p = (char*)d_ws;
    auto alloc = [&](size_t bytes) {
        char* q = p;
        p += (bytes + 255) & ~(size_t)255;
        return q;
    };
    int* rowptr = (int*)alloc((size_t)(N + 1) * 4);
    int* csr_src = (int*)alloc((size_t)E * 4);
    int* gcursor = (int*)alloc((size_t)NBK * 4);
    unsigned* bke = (unsigned*)alloc((size_t)NBK * BCAP * 4);
    float* dinv = (float*)alloc((size_t)N * 4);
    __half* h1s = (__half*)alloc((size_t)N * HIDDEN * 2);  // stride 64 halves (128B)
    __half* h2a = (__half*)alloc((size_t)N * 32 * 2);      // classes 0-31, 64B rows
    __half* h2b = (__half*)alloc((size_t)N * 8 * 2);       // classes 32-39, 16B rows

    // CSR build: memset + 2 kernels
    hipMemsetAsync(gcursor, 0, (size_t)NBK * 4, stream);
    bucket_kernel<<<(E + CHUNK - 1) / CHUNK, 256, 0, stream>>>(row, col, gcursor, bke, E);
    place_kernel<<<NBK, 256, 0, stream>>>(gcursor, bke, rowptr, dinv, csr_src, N);

    // layer 1 transform: fp32 X -> fp16 h1s (stride 64)
    gemm_mfma_kernel<float, N_FEAT, N_FEAT, HIDDEN, HIDDEN, HIDDEN>
        <<<(N + 255) / 256, 256, 0, stream>>>(x, W1, dinv, h1s, N);

    // fused: gather layer-1 (relu, b1) -> LDS -> GEMM2 -> split h2a/h2b
    gather1_gemm2_kernel<<<(N + 63) / 64, 256, 0, stream>>>(rowptr, csr_src, dinv, h1s,
                                                            b1, W2, h2a, h2b, N);

    // layer-2 gather: 12 nodes x 5 chunks = 60/64 lanes, contiguous nodes
    gather2_kernel<<<(N + 47) / 48, 256, 0, stream>>>(rowptr, csr_src, dinv, h2a, h2b,
                                                      b2, out, N);
}

// Round 6
// 205.467 us; speedup vs baseline: 1.1335x; 1.0166x over previous
//
#include <hip/hip_runtime.h>
#include <hip/hip_fp16.h>
#include <type_traits>

#define N_NODES 100000
#define N_EDGES 1200000
#define N_FEAT 128
#define HIDDEN 64
#define N_CLASSES 40

// bucket sort parameters
#define BSHIFT 9
#define BMASK 511
#define BUCKET_NODES 512
#define NBK ((N_NODES + BUCKET_NODES - 1) / BUCKET_NODES)  // 196
#define BCAP 8192
#define CHUNK 2048
#define NCHUNKS ((N_EDGES + CHUNK - 1) / CHUNK)  // 586
#define NT1 ((N_NODES + 255) / 256)              // 391 gemm1 tiles

typedef _Float16 f16x8 __attribute__((ext_vector_type(8)));
typedef float f32x4 __attribute__((ext_vector_type(4)));

// ================= K1: bucket (blocks 0..585) || gemm1 (blocks 586..976) ==========
// The two roles are independent: bucket builds the edge-bucket array from
// row/col; gemm1 computes UNSCALED h1 = fp16(X @ W1) (dinv scaling moved into
// gather1's v_fma_mix, which makes gemm1 independent of place's dinv output).
// LDS is overlaid: one 16.9KB buffer, each role casts its own layout.

__device__ __forceinline__ void bucket_role(char* smem, const int* __restrict__ row,
                                            const int* __restrict__ col,
                                            int* __restrict__ gcursor,
                                            unsigned* __restrict__ bke, int E,
                                            int chunk) {
    int* hist = (int*)smem;            // [NBK]
    int* pfx = hist + NBK;             // [NBK]
    int* gbase = pfx + NBK;            // [NBK]
    int* lcnt = gbase + NBK;           // [NBK]
    unsigned* ord = (unsigned*)(lcnt + NBK);            // [CHUNK]
    unsigned char* obkt = (unsigned char*)(ord + CHUNK);  // [CHUNK]

    const int t = threadIdx.x;
    const int e0 = chunk * CHUNK;
    const int nE = min(CHUNK, E - e0);

    for (int i = t; i < NBK; i += 256) {
        hist[i] = 0;
        lcnt[i] = 0;
    }
    __syncthreads();

    for (int i = t; i < nE; i += 256) atomicAdd(&hist[col[e0 + i] >> BSHIFT], 1);
    __syncthreads();

    int v = (t < NBK) ? hist[t] : 0;
    if (t < NBK) pfx[t] = v;
    __syncthreads();
    for (int d = 1; d < 256; d <<= 1) {
        int add = (t >= d && t < NBK) ? pfx[t - d] : 0;
        __syncthreads();
        if (t < NBK) pfx[t] += add;
        __syncthreads();
    }
    if (t < NBK) {
        pfx[t] -= v;  // exclusive
        gbase[t] = t * BCAP + ((v > 0) ? atomicAdd(&gcursor[t], v) : 0);
    }
    __syncthreads();

    for (int i = t; i < nE; i += 256) {
        int r = row[e0 + i];
        int c = col[e0 + i];
        int b = c >> BSHIFT;
        int pos = pfx[b] + atomicAdd(&lcnt[b], 1);
        ord[pos] = ((unsigned)r << BSHIFT) | (unsigned)(c & BMASK);
        obkt[pos] = (unsigned char)b;
    }
    __syncthreads();

    for (int i = t; i < nE; i += 256) {
        int b = obkt[i];
        bke[(size_t)gbase[b] + (i - pfx[b])] = ord[i];
    }
}

// gemm1: h1s[node, f] = fp16( (X @ W1)[node, f] ), row stride 64 halves. UNSCALED.
// v_mfma_f32_16x16x32_f16: A[m=lane&15][k=quad*8+j], B[k][n=lane&15],
// C: col=lane&15, row=quad*4+reg.
__device__ __forceinline__ void gemm1_role(char* smem, const float* __restrict__ X,
                                           const float* __restrict__ W,
                                           __half* __restrict__ Hs, int M, int bnode0) {
    constexpr int WPITCH = 66;
    _Float16* wh = (_Float16*)smem;  // [128 * 66]

    const int tid = threadIdx.x;

    for (int i = tid; i < N_FEAT * HIDDEN; i += 256) {
        int k = i / HIDDEN, n = i % HIDDEN;
        wh[k * WPITCH + n] = (_Float16)W[k * HIDDEN + n];
    }
    __syncthreads();

    const int wid = tid >> 6;
    const int lane = tid & 63;
    const int m = lane & 15;
    const int quad = lane >> 4;

    f16x8 bf[4][4];
#pragma unroll
    for (int kc = 0; kc < 4; ++kc)
#pragma unroll
        for (int nt = 0; nt < 4; ++nt)
#pragma unroll
            for (int j = 0; j < 8; ++j)
                bf[kc][nt][j] = wh[(kc * 32 + quad * 8 + j) * WPITCH + nt * 16 + m];

    for (int nt4 = 0; nt4 < 4; ++nt4) {
        const int nb = bnode0 + wid * 64 + nt4 * 16;
        if (nb >= M) break;
        const int rowi = min(nb + m, M - 1);
        const float* xr = X + (size_t)rowi * N_FEAT;

        f32x4 acc[4];
#pragma unroll
        for (int nt = 0; nt < 4; ++nt) acc[nt] = (f32x4){0.f, 0.f, 0.f, 0.f};

#pragma unroll
        for (int kc = 0; kc < 4; ++kc) {
            float4 u0 = *(const float4*)&xr[kc * 32 + quad * 8];
            float4 u1 = *(const float4*)&xr[kc * 32 + quad * 8 + 4];
            f16x8 af;
            af[0] = (_Float16)u0.x;
            af[1] = (_Float16)u0.y;
            af[2] = (_Float16)u0.z;
            af[3] = (_Float16)u0.w;
            af[4] = (_Float16)u1.x;
            af[5] = (_Float16)u1.y;
            af[6] = (_Float16)u1.z;
            af[7] = (_Float16)u1.w;
#pragma unroll
            for (int nt = 0; nt < 4; ++nt)
                acc[nt] = __builtin_amdgcn_mfma_f32_16x16x32_f16(af, bf[kc][nt], acc[nt], 0, 0, 0);
        }

#pragma unroll
        for (int reg = 0; reg < 4; ++reg) {
            const int node = nb + quad * 4 + reg;
            if (node < M) {
#pragma unroll
                for (int nt = 0; nt < 4; ++nt)
                    Hs[(size_t)node * HIDDEN + nt * 16 + m] = __float2half(acc[nt][reg]);
            }
        }
    }
}

__global__ __launch_bounds__(256) void k1_bucket_gemm1(const int* __restrict__ row,
                                                       const int* __restrict__ col,
                                                       int* __restrict__ gcursor,
                                                       unsigned* __restrict__ bke, int E,
                                                       const float* __restrict__ x,
                                                       const float* __restrict__ W1,
                                                       __half* __restrict__ h1s, int M) {
    __shared__ __align__(16) char smem[N_FEAT * 66 * 2];  // 16896B >= bucket's 13376B
    const int bid = blockIdx.x;
    if (bid < NCHUNKS)
        bucket_role(smem, row, col, gcursor, bke, E, bid);
    else
        gemm1_role(smem, x, W1, h1s, M, (bid - NCHUNKS) * 256);
}

// ---- fused per-bucket: bucketBase scan + hist -> rowptr + dinv -> scatter CSR ----

__global__ __launch_bounds__(256) void place_kernel(const int* __restrict__ gcursor,
                                                    const unsigned* __restrict__ bke,
                                                    int* __restrict__ rowptr,
                                                    float* __restrict__ dinv,
                                                    int* __restrict__ csr_src, int n) {
    __shared__ int hist[BUCKET_NODES];
    __shared__ int cur[BUCKET_NODES];
    __shared__ int tsum[256];

    const int b = blockIdx.x, t = threadIdx.x;
    const int node0 = b << BSHIFT;
    const int nNodes = min(BUCKET_NODES, n - node0);

    // bucket base: exclusive prefix over the 196 bucket counts (gcursor holds counts)
    const int myCnt = (t < NBK) ? gcursor[t] : 0;
    tsum[t] = myCnt;
    __syncthreads();
    for (int d = 1; d < 256; d <<= 1) {
        int add = (t >= d) ? tsum[t - d] : 0;
        __syncthreads();
        tsum[t] += add;
        __syncthreads();
    }
    const int base = tsum[b] - gcursor[b];  // exclusive prefix at b
    const int nb = gcursor[b];
    __syncthreads();

    hist[t] = 0;
    hist[t + 256] = 0;
    __syncthreads();

    const unsigned* src = bke + (size_t)b * BCAP;
    for (int i = t; i < nb; i += 256) atomicAdd(&hist[src[i] & BMASK], 1);
    __syncthreads();

    // 512-wide exclusive scan: thread t owns elements 2t, 2t+1
    const int c0 = hist[2 * t];
    const int c1 = hist[2 * t + 1];
    const int s = c0 + c1;
    tsum[t] = s;
    __syncthreads();
    for (int d = 1; d < 256; d <<= 1) {
        int add = (t >= d) ? tsum[t - d] : 0;
        __syncthreads();
        tsum[t] += add;
        __syncthreads();
    }
    const int e0 = base + tsum[t] - s;
    const int e1 = e0 + c0;

    cur[2 * t] = e0;
    cur[2 * t + 1] = e1;
    if (2 * t < nNodes) {
        rowptr[node0 + 2 * t] = e0;
        dinv[node0 + 2 * t] = rsqrtf((float)(c0 + 1));
    }
    if (2 * t + 1 < nNodes) {
        rowptr[node0 + 2 * t + 1] = e1;
        dinv[node0 + 2 * t + 1] = rsqrtf((float)(c1 + 1));
    }
    if (t == 0 && node0 + nNodes == n) rowptr[n] = N_EDGES;
    __syncthreads();

    for (int i = t; i < nb; i += 256) {
        unsigned p = src[i];
        int pos = atomicAdd(&cur[p & BMASK], 1);
        csr_src[pos] = (int)(p >> BSHIFT);
    }
}

// ---------------- gather accumulate primitive ----------------
// v_fma_mix_f32: acc += (float)h16 * s -- exact f16->f32 promote, f32 multiply,
// 1 instr/feature. s=1.0f for pre-scaled rows, s=dinv[r] for unscaled h1 rows.

__device__ inline void acc_mix16(float (&acc)[8], uint4 u, float s) {
    const unsigned* w = (const unsigned*)&u;
#pragma unroll
    for (int k = 0; k < 4; ++k) {
        asm("v_fma_mix_f32 %0, %1, %2, %0 op_sel:[0,0,0] op_sel_hi:[1,0,0]"
            : "+v"(acc[2 * k])
            : "v"(w[k]), "v"(s));
        asm("v_fma_mix_f32 %0, %1, %2, %0 op_sel:[1,0,0] op_sel_hi:[1,0,0]"
            : "+v"(acc[2 * k + 1])
            : "v"(w[k]), "v"(s));
    }
}

// ---------------- fused gather1 + GEMM2 ----------------
// Block = 256 threads, 64 nodes. Phase 1: each wave handles 8 nodes/round x 2
// rounds; group g (8 lanes) owns one node, lane q one 16B chunk; aggregate
// UNSCALED h1s rows with per-edge weight dinv[r] (self weight dinv[c]) via
// v_fma_mix, apply dinv[c]/b1/relu, store fp16 row to LDS. Phase 2: 64x64x40
// MFMA tile from LDS (A = agg rows, B = W2 fp16), epilogue writes SPLIT h2:
// classes 0-31 -> h2a (64B rows = 1 line/edge-read), 32-39 -> h2b (16B rows,
// 1.6MB L2-resident). Final values match the reference formula exactly:
// out = dinv_c * sum_r(dinv_r * h_r) + b.

__global__ __launch_bounds__(256) void gather1_gemm2_kernel(
    const int* __restrict__ rowptr, const int* __restrict__ csr_src,
    const float* __restrict__ dinv, const __half* __restrict__ h1s,
    const float* __restrict__ b1, const float* __restrict__ W2,
    __half* __restrict__ h2a, __half* __restrict__ h2b, int n) {
    constexpr int APITCH = 72;  // halves; 144B rows keep 16B alignment for b128 LDS ops
    constexpr int WPITCH = 50;

    __shared__ _Float16 agg[64 * APITCH];
    __shared__ _Float16 wh[64 * WPITCH];
    __shared__ float sdinv[64];

    const int tid = threadIdx.x;
    const int base = blockIdx.x * 64;

    // stage W2 (64x40, zero-padded to 48 cols) and this block's dinv
    for (int i = tid; i < 64 * 48; i += 256) {
        int k = i / 48, nn = i % 48;
        wh[k * WPITCH + nn] = (nn < 40) ? (_Float16)W2[k * 40 + nn] : (_Float16)0.0f;
    }
    if (tid < 64) {
        int node = base + tid;
        sdinv[tid] = (node < n) ? dinv[node] : 0.f;
    }
    __syncthreads();

    const int wid = tid >> 6;
    const int lane = tid & 63;
    const int g = lane >> 3;  // node slot within wave
    const int q = lane & 7;   // 16B chunk within 128B row
    const __half* hq = h1s + q * 8;

    // ---- phase 1: gather 64 nodes into LDS (2 rounds of 8 nodes/wave) ----
#pragma unroll
    for (int t = 0; t < 2; ++t) {
        const int nl = t * 32 + wid * 8 + g;
        const int c = base + nl;
        if (c < n) {
            float acc[8];
#pragma unroll
            for (int j = 0; j < 8; ++j) acc[j] = 0.f;

            const float dc = sdinv[nl];
            // self loop, weight dinv[c]
            acc_mix16(acc, *(const uint4*)(hq + (size_t)c * HIDDEN), dc);

            int e = rowptr[c];
            const int eEnd = rowptr[c + 1];
            for (; e + 2 <= eEnd; e += 2) {
                int r0 = csr_src[e];
                int r1 = csr_src[e + 1];
                float s0 = dinv[r0];
                float s1 = dinv[r1];
                uint4 u0 = *(const uint4*)(hq + (size_t)r0 * HIDDEN);
                uint4 u1 = *(const uint4*)(hq + (size_t)r1 * HIDDEN);
                acc_mix16(acc, u0, s0);
                acc_mix16(acc, u1, s1);
            }
            if (e < eEnd) {
                int r = csr_src[e];
                acc_mix16(acc, *(const uint4*)(hq + (size_t)r * HIDDEN), dinv[r]);
            }

            _Float16 hv[8];
#pragma unroll
            for (int j = 0; j < 8; ++j) {
                float v = fmaf(acc[j], dc, b1[q * 8 + j]);
                hv[j] = (_Float16)fmaxf(v, 0.f);
            }
            *(f16x8*)&agg[nl * APITCH + q * 8] = *(f16x8*)hv;
        }
    }
    __syncthreads();

    // ---- phase 2: GEMM2 on the 64 LDS rows ----
    const int m = lane & 15;
    const int quad = lane >> 4;

    f16x8 bf[2][3];
#pragma unroll
    for (int kc = 0; kc < 2; ++kc)
#pragma unroll
        for (int nt = 0; nt < 3; ++nt)
#pragma unroll
            for (int j = 0; j < 8; ++j)
                bf[kc][nt][j] = wh[(kc * 32 + quad * 8 + j) * WPITCH + nt * 16 + m];

    const int nl0 = wid * 16;  // this wave's 16-node tile

    f32x4 acc2[3];
#pragma unroll
    for (int nt = 0; nt < 3; ++nt) acc2[nt] = (f32x4){0.f, 0.f, 0.f, 0.f};

#pragma unroll
    for (int kc = 0; kc < 2; ++kc) {
        f16x8 af = *(const f16x8*)&agg[(nl0 + m) * APITCH + kc * 32 + quad * 8];
#pragma unroll
        for (int nt = 0; nt < 3; ++nt)
            acc2[nt] = __builtin_amdgcn_mfma_f32_16x16x32_f16(af, bf[kc][nt], acc2[nt], 0, 0, 0);
    }

#pragma unroll
    for (int reg = 0; reg < 4; ++reg) {
        const int nl = nl0 + quad * 4 + reg;
        const int node = base + nl;
        if (node < n) {
            const float s = sdinv[nl];
#pragma unroll
            for (int nt = 0; nt < 3; ++nt) {
                const int f = nt * 16 + m;
                const __half hv = __float2half(acc2[nt][reg] * s);
                if (f < 32)
                    h2a[(size_t)node * 32 + f] = hv;
                else if (f < N_CLASSES)
                    h2b[(size_t)node * 8 + (f - 32)] = hv;
            }
        }
    }
}

// ---------------- layer-2 gather: 12 nodes x 5 chunks, split h2a/h2b ----------------
// Contiguous node blocks (R2 showed locality >> balance). q<4 lanes read 16B
// chunks of h2a (stride 32 halves, 1 line/row); q==4 reads h2b (stride 8,
// L2-resident). h2 rows are pre-scaled by dinv_r -> weight-1 accumulate.

__global__ __launch_bounds__(256) void gather2_kernel(const int* __restrict__ rowptr,
                                                      const int* __restrict__ csr_src,
                                                      const float* __restrict__ dinv,
                                                      const __half* __restrict__ h2a,
                                                      const __half* __restrict__ h2b,
                                                      const float* __restrict__ bias,
                                                      float* __restrict__ out, int n) {
    const int wave = (blockIdx.x * blockDim.x + threadIdx.x) >> 6;
    const int lane = threadIdx.x & 63;
    if (lane >= 60) return;
    const int g = lane / 5;  // node slot within wave
    const int q = lane % 5;  // feature chunk
    const int c = wave * 12 + g;
    if (c >= n) return;

    const float one = 1.0f;
    const __half* hq = (q < 4) ? (h2a + q * 8) : h2b;
    const int sh = (q < 4) ? 5 : 3;  // log2(row stride in halves)

    const int eBeg = rowptr[c];
    const int eEnd = rowptr[c + 1];

    float acc[8];
#pragma unroll
    for (int j = 0; j < 8; ++j) acc[j] = 0.f;

    // self loop
    acc_mix16(acc, *(const uint4*)(hq + ((size_t)c << sh)), one);

    int e = eBeg;
    for (; e + 2 <= eEnd; e += 2) {
        int r0 = csr_src[e];
        int r1 = csr_src[e + 1];
        uint4 u0 = *(const uint4*)(hq + ((size_t)r0 << sh));
        uint4 u1 = *(const uint4*)(hq + ((size_t)r1 << sh));
        acc_mix16(acc, u0, one);
        acc_mix16(acc, u1, one);
    }
    if (e < eEnd) {
        int r = csr_src[e];
        acc_mix16(acc, *(const uint4*)(hq + ((size_t)r << sh)), one);
    }

    const float dc = dinv[c];
    float o[8];
#pragma unroll
    for (int j = 0; j < 8; ++j) {
        float v = fmaf(acc[j], dc, bias[q * 8 + j]);
        o[j] = v;
    }

    float* dst = &out[(size_t)c * N_CLASSES + q * 8];
    *(float4*)dst = make_float4(o[0], o[1], o[2], o[3]);
    *(float4*)(dst + 4) = make_float4(o[4], o[5], o[6], o[7]);
}

// ---------------- launch ----------------

extern "C" void kernel_launch(void* const* d_in, const int* in_sizes, int n_in,
                              void* d_out, int out_size, void* d_ws, size_t ws_size,
                              hipStream_t stream) {
    const float* x = (const float*)d_in[0];
    const int* row = (const int*)d_in[1];
    const int* col = row + N_EDGES;
    const float* W1 = (const float*)d_in[2];
    const float* b1 = (const float*)d_in[3];
    const float* W2 = (const float*)d_in[4];
    const float* b2 = (const float*)d_in[5];
    float* out = (float*)d_out;

    const int N = N_NODES, E = N_EDGES;

    // 256B-aligned workspace carve-up: h1s rows 128B-aligned (2 lines/row),
    // h2a rows 64B-aligned (exactly 1 line/row), h2b 16B rows.
    char* p = (char*)d_ws;
    auto alloc = [&](size_t bytes) {
        char* q = p;
        p += (bytes + 255) & ~(size_t)255;
        return q;
    };
    int* rowptr = (int*)alloc((size_t)(N + 1) * 4);
    int* csr_src = (int*)alloc((size_t)E * 4);
    int* gcursor = (int*)alloc((size_t)NBK * 4);
    unsigned* bke = (unsigned*)alloc((size_t)NBK * BCAP * 4);
    float* dinv = (float*)alloc((size_t)N * 4);
    __half* h1s = (__half*)alloc((size_t)N * HIDDEN * 2);  // stride 64 halves (128B)
    __half* h2a = (__half*)alloc((size_t)N * 32 * 2);      // classes 0-31, 64B rows
    __half* h2b = (__half*)alloc((size_t)N * 8 * 2);       // classes 32-39, 16B rows

    hipMemsetAsync(gcursor, 0, (size_t)NBK * 4, stream);

    // K1: bucket (586 blocks) || gemm1 unscaled (391 blocks) -- independent roles
    k1_bucket_gemm1<<<NCHUNKS + NT1, 256, 0, stream>>>(row, col, gcursor, bke, E,
                                                       x, W1, h1s, N);

    // place: bke -> rowptr/dinv/csr_src
    place_kernel<<<NBK, 256, 0, stream>>>(gcursor, bke, rowptr, dinv, csr_src, N);

    // fused: gather layer-1 (per-edge dinv weight, relu, b1) -> LDS -> GEMM2 -> h2a/h2b
    gather1_gemm2_kernel<<<(N + 63) / 64, 256, 0, stream>>>(rowptr, csr_src, dinv, h1s,
                                                            b1, W2, h2a, h2b, N);

    // layer-2 gather: 12 nodes x 5 chunks = 60/64 lanes, contiguous nodes
    gather2_kernel<<<(N + 47) / 48, 256, 0, stream>>>(rowptr, csr_src, dinv, h2a, h2b,
                                                      b2, out, N);
}

// Round 7
// 200.571 us; speedup vs baseline: 1.1612x; 1.0244x over previous
//
#include <hip/hip_runtime.h>
#include <hip/hip_fp16.h>
#include <type_traits>

#define N_NODES 100000
#define N_EDGES 1200000
#define N_FEAT 128
#define HIDDEN 64
#define N_CLASSES 40

// bucket sort parameters
#define BSHIFT 9
#define BMASK 511
#define BUCKET_NODES 512
#define NBK ((N_NODES + BUCKET_NODES - 1) / BUCKET_NODES)  // 196
#define BCAP 8192
#define CHUNK 2048
#define NCHUNKS ((N_EDGES + CHUNK - 1) / CHUNK)  // 586
#define NT1 ((N_NODES + 255) / 256)              // 391 gemm1 tiles

typedef _Float16 f16x8 __attribute__((ext_vector_type(8)));
typedef float f32x4 __attribute__((ext_vector_type(4)));

// ================= K1: bucket (blocks 0..585) || gemm1 (blocks 586..976) ==========
// The two roles are independent: bucket builds the edge-bucket array from
// row/col; gemm1 computes UNSCALED h1 = fp16(X @ W1) (dinv scaling lives in
// gather1's v_fma_mix, which makes gemm1 independent of place's dinv output).
// LDS is overlaid: one 16.9KB buffer, each role casts its own layout.

__device__ __forceinline__ void bucket_role(char* smem, const int* __restrict__ row,
                                            const int* __restrict__ col,
                                            int* __restrict__ gcursor,
                                            unsigned* __restrict__ bke, int E,
                                            int chunk) {
    int* hist = (int*)smem;            // [NBK]
    int* pfx = hist + NBK;             // [NBK]
    int* gbase = pfx + NBK;            // [NBK]
    int* lcnt = gbase + NBK;           // [NBK]
    unsigned* ord = (unsigned*)(lcnt + NBK);            // [CHUNK]
    unsigned char* obkt = (unsigned char*)(ord + CHUNK);  // [CHUNK]

    const int t = threadIdx.x;
    const int e0 = chunk * CHUNK;
    const int nE = min(CHUNK, E - e0);

    for (int i = t; i < NBK; i += 256) {
        hist[i] = 0;
        lcnt[i] = 0;
    }
    __syncthreads();

    for (int i = t; i < nE; i += 256) atomicAdd(&hist[col[e0 + i] >> BSHIFT], 1);
    __syncthreads();

    int v = (t < NBK) ? hist[t] : 0;
    if (t < NBK) pfx[t] = v;
    __syncthreads();
    for (int d = 1; d < 256; d <<= 1) {
        int add = (t >= d && t < NBK) ? pfx[t - d] : 0;
        __syncthreads();
        if (t < NBK) pfx[t] += add;
        __syncthreads();
    }
    if (t < NBK) {
        pfx[t] -= v;  // exclusive
        gbase[t] = t * BCAP + ((v > 0) ? atomicAdd(&gcursor[t], v) : 0);
    }
    __syncthreads();

    for (int i = t; i < nE; i += 256) {
        int r = row[e0 + i];
        int c = col[e0 + i];
        int b = c >> BSHIFT;
        int pos = pfx[b] + atomicAdd(&lcnt[b], 1);
        ord[pos] = ((unsigned)r << BSHIFT) | (unsigned)(c & BMASK);
        obkt[pos] = (unsigned char)b;
    }
    __syncthreads();

    for (int i = t; i < nE; i += 256) {
        int b = obkt[i];
        bke[(size_t)gbase[b] + (i - pfx[b])] = ord[i];
    }
}

// gemm1: h1s[node, f] = fp16( (X @ W1)[node, f] ), row stride 64 halves. UNSCALED.
// v_mfma_f32_16x16x32_f16: A[m=lane&15][k=quad*8+j], B[k][n=lane&15],
// C: col=lane&15, row=quad*4+reg.
__device__ __forceinline__ void gemm1_role(char* smem, const float* __restrict__ X,
                                           const float* __restrict__ W,
                                           __half* __restrict__ Hs, int M, int bnode0) {
    constexpr int WPITCH = 66;
    _Float16* wh = (_Float16*)smem;  // [128 * 66]

    const int tid = threadIdx.x;

    for (int i = tid; i < N_FEAT * HIDDEN; i += 256) {
        int k = i / HIDDEN, n = i % HIDDEN;
        wh[k * WPITCH + n] = (_Float16)W[k * HIDDEN + n];
    }
    __syncthreads();

    const int wid = tid >> 6;
    const int lane = tid & 63;
    const int m = lane & 15;
    const int quad = lane >> 4;

    f16x8 bf[4][4];
#pragma unroll
    for (int kc = 0; kc < 4; ++kc)
#pragma unroll
        for (int nt = 0; nt < 4; ++nt)
#pragma unroll
            for (int j = 0; j < 8; ++j)
                bf[kc][nt][j] = wh[(kc * 32 + quad * 8 + j) * WPITCH + nt * 16 + m];

    for (int nt4 = 0; nt4 < 4; ++nt4) {
        const int nb = bnode0 + wid * 64 + nt4 * 16;
        if (nb >= M) break;
        const int rowi = min(nb + m, M - 1);
        const float* xr = X + (size_t)rowi * N_FEAT;

        f32x4 acc[4];
#pragma unroll
        for (int nt = 0; nt < 4; ++nt) acc[nt] = (f32x4){0.f, 0.f, 0.f, 0.f};

#pragma unroll
        for (int kc = 0; kc < 4; ++kc) {
            float4 u0 = *(const float4*)&xr[kc * 32 + quad * 8];
            float4 u1 = *(const float4*)&xr[kc * 32 + quad * 8 + 4];
            f16x8 af;
            af[0] = (_Float16)u0.x;
            af[1] = (_Float16)u0.y;
            af[2] = (_Float16)u0.z;
            af[3] = (_Float16)u0.w;
            af[4] = (_Float16)u1.x;
            af[5] = (_Float16)u1.y;
            af[6] = (_Float16)u1.z;
            af[7] = (_Float16)u1.w;
#pragma unroll
            for (int nt = 0; nt < 4; ++nt)
                acc[nt] = __builtin_amdgcn_mfma_f32_16x16x32_f16(af, bf[kc][nt], acc[nt], 0, 0, 0);
        }

#pragma unroll
        for (int reg = 0; reg < 4; ++reg) {
            const int node = nb + quad * 4 + reg;
            if (node < M) {
#pragma unroll
                for (int nt = 0; nt < 4; ++nt)
                    Hs[(size_t)node * HIDDEN + nt * 16 + m] = __float2half(acc[nt][reg]);
            }
        }
    }
}

__global__ __launch_bounds__(256) void k1_bucket_gemm1(const int* __restrict__ row,
                                                       const int* __restrict__ col,
                                                       int* __restrict__ gcursor,
                                                       unsigned* __restrict__ bke, int E,
                                                       const float* __restrict__ x,
                                                       const float* __restrict__ W1,
                                                       __half* __restrict__ h1s, int M) {
    __shared__ __align__(16) char smem[N_FEAT * 66 * 2];  // 16896B >= bucket's 13376B
    const int bid = blockIdx.x;
    if (bid < NCHUNKS)
        bucket_role(smem, row, col, gcursor, bke, E, bid);
    else
        gemm1_role(smem, x, W1, h1s, M, (bid - NCHUNKS) * 256);
}

// ---- fused per-bucket: bucketBase scan + hist -> rowptr + dinv -> scatter CSR ----

__global__ __launch_bounds__(256) void place_kernel(const int* __restrict__ gcursor,
                                                    const unsigned* __restrict__ bke,
                                                    int* __restrict__ rowptr,
                                                    float* __restrict__ dinv,
                                                    int* __restrict__ csr_src, int n) {
    __shared__ int hist[BUCKET_NODES];
    __shared__ int cur[BUCKET_NODES];
    __shared__ int tsum[256];

    const int b = blockIdx.x, t = threadIdx.x;
    const int node0 = b << BSHIFT;
    const int nNodes = min(BUCKET_NODES, n - node0);

    // bucket base: exclusive prefix over the 196 bucket counts (gcursor holds counts)
    const int myCnt = (t < NBK) ? gcursor[t] : 0;
    tsum[t] = myCnt;
    __syncthreads();
    for (int d = 1; d < 256; d <<= 1) {
        int add = (t >= d) ? tsum[t - d] : 0;
        __syncthreads();
        tsum[t] += add;
        __syncthreads();
    }
    const int base = tsum[b] - gcursor[b];  // exclusive prefix at b
    const int nb = gcursor[b];
    __syncthreads();

    hist[t] = 0;
    hist[t + 256] = 0;
    __syncthreads();

    const unsigned* src = bke + (size_t)b * BCAP;
    for (int i = t; i < nb; i += 256) atomicAdd(&hist[src[i] & BMASK], 1);
    __syncthreads();

    // 512-wide exclusive scan: thread t owns elements 2t, 2t+1
    const int c0 = hist[2 * t];
    const int c1 = hist[2 * t + 1];
    const int s = c0 + c1;
    tsum[t] = s;
    __syncthreads();
    for (int d = 1; d < 256; d <<= 1) {
        int add = (t >= d) ? tsum[t - d] : 0;
        __syncthreads();
        tsum[t] += add;
        __syncthreads();
    }
    const int e0 = base + tsum[t] - s;
    const int e1 = e0 + c0;

    cur[2 * t] = e0;
    cur[2 * t + 1] = e1;
    if (2 * t < nNodes) {
        rowptr[node0 + 2 * t] = e0;
        dinv[node0 + 2 * t] = rsqrtf((float)(c0 + 1));
    }
    if (2 * t + 1 < nNodes) {
        rowptr[node0 + 2 * t + 1] = e1;
        dinv[node0 + 2 * t + 1] = rsqrtf((float)(c1 + 1));
    }
    if (t == 0 && node0 + nNodes == n) rowptr[n] = N_EDGES;
    __syncthreads();

    for (int i = t; i < nb; i += 256) {
        unsigned p = src[i];
        int pos = atomicAdd(&cur[p & BMASK], 1);
        csr_src[pos] = (int)(p >> BSHIFT);
    }
}

// ---------------- gather accumulate primitive ----------------
// v_fma_mix_f32: acc += (float)h16 * s -- exact f16->f32 promote, f32 multiply,
// 1 instr/feature. s=1.0f for pre-scaled rows, s=dinv[r] for unscaled h1 rows.

__device__ inline void acc_mix16(float (&acc)[8], uint4 u, float s) {
    const unsigned* w = (const unsigned*)&u;
#pragma unroll
    for (int k = 0; k < 4; ++k) {
        asm("v_fma_mix_f32 %0, %1, %2, %0 op_sel:[0,0,0] op_sel_hi:[1,0,0]"
            : "+v"(acc[2 * k])
            : "v"(w[k]), "v"(s));
        asm("v_fma_mix_f32 %0, %1, %2, %0 op_sel:[1,0,0] op_sel_hi:[1,0,0]"
            : "+v"(acc[2 * k + 1])
            : "v"(w[k]), "v"(s));
    }
}

// ---------------- fused gather1 + GEMM2 ----------------
// Block = 256 threads, 64 nodes. Phase 1: each wave handles 8 nodes/round x 2
// rounds; group g (8 lanes) owns one node, lane q one 16B chunk; aggregate
// UNSCALED h1s rows with per-edge weight dinv[r] (self weight dinv[c]) via
// v_fma_mix, 4-deep edge unroll (latency-bound loop: 4 rows + 4 idx + 4 dinv
// in flight halves the dependent-round count vs 2-deep), apply dinv[c]/b1/relu,
// store fp16 row to LDS. Phase 2: 64x64x40 MFMA tile from LDS, epilogue writes
// SPLIT h2: classes 0-31 -> h2a (64B rows = 1 line/edge-read), 32-39 -> h2b
// (16B rows, 1.6MB L2-resident). out = dinv_c * sum_r(dinv_r * h_r) + b.

__global__ __launch_bounds__(256) void gather1_gemm2_kernel(
    const int* __restrict__ rowptr, const int* __restrict__ csr_src,
    const float* __restrict__ dinv, const __half* __restrict__ h1s,
    const float* __restrict__ b1, const float* __restrict__ W2,
    __half* __restrict__ h2a, __half* __restrict__ h2b, int n) {
    constexpr int APITCH = 72;  // halves; 144B rows keep 16B alignment for b128 LDS ops
    constexpr int WPITCH = 50;

    __shared__ _Float16 agg[64 * APITCH];
    __shared__ _Float16 wh[64 * WPITCH];
    __shared__ float sdinv[64];

    const int tid = threadIdx.x;
    const int base = blockIdx.x * 64;

    // stage W2 (64x40, zero-padded to 48 cols) and this block's dinv
    for (int i = tid; i < 64 * 48; i += 256) {
        int k = i / 48, nn = i % 48;
        wh[k * WPITCH + nn] = (nn < 40) ? (_Float16)W2[k * 40 + nn] : (_Float16)0.0f;
    }
    if (tid < 64) {
        int node = base + tid;
        sdinv[tid] = (node < n) ? dinv[node] : 0.f;
    }
    __syncthreads();

    const int wid = tid >> 6;
    const int lane = tid & 63;
    const int g = lane >> 3;  // node slot within wave
    const int q = lane & 7;   // 16B chunk within 128B row
    const __half* hq = h1s + q * 8;

    // ---- phase 1: gather 64 nodes into LDS (2 rounds of 8 nodes/wave) ----
#pragma unroll
    for (int t = 0; t < 2; ++t) {
        const int nl = t * 32 + wid * 8 + g;
        const int c = base + nl;
        if (c < n) {
            float acc[8];
#pragma unroll
            for (int j = 0; j < 8; ++j) acc[j] = 0.f;

            const float dc = sdinv[nl];
            // self loop, weight dinv[c]
            acc_mix16(acc, *(const uint4*)(hq + (size_t)c * HIDDEN), dc);

            int e = rowptr[c];
            const int eEnd = rowptr[c + 1];
            for (; e + 4 <= eEnd; e += 4) {
                int r0 = csr_src[e];
                int r1 = csr_src[e + 1];
                int r2 = csr_src[e + 2];
                int r3 = csr_src[e + 3];
                float s0 = dinv[r0];
                float s1 = dinv[r1];
                float s2 = dinv[r2];
                float s3 = dinv[r3];
                uint4 u0 = *(const uint4*)(hq + (size_t)r0 * HIDDEN);
                uint4 u1 = *(const uint4*)(hq + (size_t)r1 * HIDDEN);
                uint4 u2 = *(const uint4*)(hq + (size_t)r2 * HIDDEN);
                uint4 u3 = *(const uint4*)(hq + (size_t)r3 * HIDDEN);
                acc_mix16(acc, u0, s0);
                acc_mix16(acc, u1, s1);
                acc_mix16(acc, u2, s2);
                acc_mix16(acc, u3, s3);
            }
            if (e + 2 <= eEnd) {
                int r0 = csr_src[e];
                int r1 = csr_src[e + 1];
                float s0 = dinv[r0];
                float s1 = dinv[r1];
                uint4 u0 = *(const uint4*)(hq + (size_t)r0 * HIDDEN);
                uint4 u1 = *(const uint4*)(hq + (size_t)r1 * HIDDEN);
                acc_mix16(acc, u0, s0);
                acc_mix16(acc, u1, s1);
                e += 2;
            }
            if (e < eEnd) {
                int r = csr_src[e];
                acc_mix16(acc, *(const uint4*)(hq + (size_t)r * HIDDEN), dinv[r]);
            }

            _Float16 hv[8];
#pragma unroll
            for (int j = 0; j < 8; ++j) {
                float v = fmaf(acc[j], dc, b1[q * 8 + j]);
                hv[j] = (_Float16)fmaxf(v, 0.f);
            }
            *(f16x8*)&agg[nl * APITCH + q * 8] = *(f16x8*)hv;
        }
    }
    __syncthreads();

    // ---- phase 2: GEMM2 on the 64 LDS rows ----
    const int m = lane & 15;
    const int quad = lane >> 4;

    f16x8 bf[2][3];
#pragma unroll
    for (int kc = 0; kc < 2; ++kc)
#pragma unroll
        for (int nt = 0; nt < 3; ++nt)
#pragma unroll
            for (int j = 0; j < 8; ++j)
                bf[kc][nt][j] = wh[(kc * 32 + quad * 8 + j) * WPITCH + nt * 16 + m];

    const int nl0 = wid * 16;  // this wave's 16-node tile

    f32x4 acc2[3];
#pragma unroll
    for (int nt = 0; nt < 3; ++nt) acc2[nt] = (f32x4){0.f, 0.f, 0.f, 0.f};

#pragma unroll
    for (int kc = 0; kc < 2; ++kc) {
        f16x8 af = *(const f16x8*)&agg[(nl0 + m) * APITCH + kc * 32 + quad * 8];
#pragma unroll
        for (int nt = 0; nt < 3; ++nt)
            acc2[nt] = __builtin_amdgcn_mfma_f32_16x16x32_f16(af, bf[kc][nt], acc2[nt], 0, 0, 0);
    }

#pragma unroll
    for (int reg = 0; reg < 4; ++reg) {
        const int nl = nl0 + quad * 4 + reg;
        const int node = base + nl;
        if (node < n) {
            const float s = sdinv[nl];
#pragma unroll
            for (int nt = 0; nt < 3; ++nt) {
                const int f = nt * 16 + m;
                const __half hv = __float2half(acc2[nt][reg] * s);
                if (f < 32)
                    h2a[(size_t)node * 32 + f] = hv;
                else if (f < N_CLASSES)
                    h2b[(size_t)node * 8 + (f - 32)] = hv;
            }
        }
    }
}

// ---------------- layer-2 gather: 12 nodes x 5 chunks, split h2a/h2b ----------------
// Contiguous node blocks (R2 showed locality >> balance). q<4 lanes read 16B
// chunks of h2a (stride 32 halves, 1 line/row); q==4 reads h2b (stride 8,
// L2-resident). h2 rows are pre-scaled by dinv_r -> weight-1 accumulate.
// 4-deep edge unroll for latency hiding (same rationale as gather1).

__global__ __launch_bounds__(256) void gather2_kernel(const int* __restrict__ rowptr,
                                                      const int* __restrict__ csr_src,
                                                      const float* __restrict__ dinv,
                                                      const __half* __restrict__ h2a,
                                                      const __half* __restrict__ h2b,
                                                      const float* __restrict__ bias,
                                                      float* __restrict__ out, int n) {
    const int wave = (blockIdx.x * blockDim.x + threadIdx.x) >> 6;
    const int lane = threadIdx.x & 63;
    if (lane >= 60) return;
    const int g = lane / 5;  // node slot within wave
    const int q = lane % 5;  // feature chunk
    const int c = wave * 12 + g;
    if (c >= n) return;

    const float one = 1.0f;
    const __half* hq = (q < 4) ? (h2a + q * 8) : h2b;
    const int sh = (q < 4) ? 5 : 3;  // log2(row stride in halves)

    const int eBeg = rowptr[c];
    const int eEnd = rowptr[c + 1];

    float acc[8];
#pragma unroll
    for (int j = 0; j < 8; ++j) acc[j] = 0.f;

    // self loop
    acc_mix16(acc, *(const uint4*)(hq + ((size_t)c << sh)), one);

    int e = eBeg;
    for (; e + 4 <= eEnd; e += 4) {
        int r0 = csr_src[e];
        int r1 = csr_src[e + 1];
        int r2 = csr_src[e + 2];
        int r3 = csr_src[e + 3];
        uint4 u0 = *(const uint4*)(hq + ((size_t)r0 << sh));
        uint4 u1 = *(const uint4*)(hq + ((size_t)r1 << sh));
        uint4 u2 = *(const uint4*)(hq + ((size_t)r2 << sh));
        uint4 u3 = *(const uint4*)(hq + ((size_t)r3 << sh));
        acc_mix16(acc, u0, one);
        acc_mix16(acc, u1, one);
        acc_mix16(acc, u2, one);
        acc_mix16(acc, u3, one);
    }
    if (e + 2 <= eEnd) {
        int r0 = csr_src[e];
        int r1 = csr_src[e + 1];
        uint4 u0 = *(const uint4*)(hq + ((size_t)r0 << sh));
        uint4 u1 = *(const uint4*)(hq + ((size_t)r1 << sh));
        acc_mix16(acc, u0, one);
        acc_mix16(acc, u1, one);
        e += 2;
    }
    if (e < eEnd) {
        int r = csr_src[e];
        acc_mix16(acc, *(const uint4*)(hq + ((size_t)r << sh)), one);
    }

    const float dc = dinv[c];
    float o[8];
#pragma unroll
    for (int j = 0; j < 8; ++j) {
        float v = fmaf(acc[j], dc, bias[q * 8 + j]);
        o[j] = v;
    }

    float* dst = &out[(size_t)c * N_CLASSES + q * 8];
    *(float4*)dst = make_float4(o[0], o[1], o[2], o[3]);
    *(float4*)(dst + 4) = make_float4(o[4], o[5], o[6], o[7]);
}

// ---------------- launch ----------------

extern "C" void kernel_launch(void* const* d_in, const int* in_sizes, int n_in,
                              void* d_out, int out_size, void* d_ws, size_t ws_size,
                              hipStream_t stream) {
    const float* x = (const float*)d_in[0];
    const int* row = (const int*)d_in[1];
    const int* col = row + N_EDGES;
    const float* W1 = (const float*)d_in[2];
    const float* b1 = (const float*)d_in[3];
    const float* W2 = (const float*)d_in[4];
    const float* b2 = (const float*)d_in[5];
    float* out = (float*)d_out;

    const int N = N_NODES, E = N_EDGES;

    // 256B-aligned workspace carve-up: h1s rows 128B-aligned (2 lines/row),
    // h2a rows 64B-aligned (exactly 1 line/row), h2b 16B rows.
    char* p = (char*)d_ws;
    auto alloc = [&](size_t bytes) {
        char* q = p;
        p += (bytes + 255) & ~(size_t)255;
        return q;
    };
    int* rowptr = (int*)alloc((size_t)(N + 1) * 4);
    int* csr_src = (int*)alloc((size_t)E * 4);
    int* gcursor = (int*)alloc((size_t)NBK * 4);
    unsigned* bke = (unsigned*)alloc((size_t)NBK * BCAP * 4);
    float* dinv = (float*)alloc((size_t)N * 4);
    __half* h1s = (__half*)alloc((size_t)N * HIDDEN * 2);  // stride 64 halves (128B)
    __half* h2a = (__half*)alloc((size_t)N * 32 * 2);      // classes 0-31, 64B rows
    __half* h2b = (__half*)alloc((size_t)N * 8 * 2);       // classes 32-39, 16B rows

    hipMemsetAsync(gcursor, 0, (size_t)NBK * 4, stream);

    // K1: bucket (586 blocks) || gemm1 unscaled (391 blocks) -- independent roles
    k1_bucket_gemm1<<<NCHUNKS + NT1, 256, 0, stream>>>(row, col, gcursor, bke, E,
                                                       x, W1, h1s, N);

    // place: bke -> rowptr/dinv/csr_src
    place_kernel<<<NBK, 256, 0, stream>>>(gcursor, bke, rowptr, dinv, csr_src, N);

    // fused: gather layer-1 (per-edge dinv weight, relu, b1) -> LDS -> GEMM2 -> h2a/h2b
    gather1_gemm2_kernel<<<(N + 63) / 64, 256, 0, stream>>>(rowptr, csr_src, dinv, h1s,
                                                            b1, W2, h2a, h2b, N);

    // layer-2 gather: 12 nodes x 5 chunks = 60/64 lanes, contiguous nodes
    gather2_kernel<<<(N + 47) / 48, 256, 0, stream>>>(rowptr, csr_src, dinv, h2a, h2b,
                                                      b2, out, N);
}

// Round 10
// 197.889 us; speedup vs baseline: 1.1769x; 1.0136x over previous
//
#include <hip/hip_runtime.h>
#include <hip/hip_fp16.h>
#include <type_traits>

#define N_NODES 100000
#define N_EDGES 1200000
#define N_FEAT 128
#define HIDDEN 64
#define N_CLASSES 40

// bucket sort parameters
#define BSHIFT 9
#define BMASK 511
#define BUCKET_NODES 512
#define NBK ((N_NODES + BUCKET_NODES - 1) / BUCKET_NODES)  // 196
#define BCAP 8192
#define CHUNK 2048
#define NCHUNKS ((N_EDGES + CHUNK - 1) / CHUNK)  // 586
#define NT1 ((N_NODES + 255) / 256)              // 391 gemm1 tiles

typedef _Float16 f16x8 __attribute__((ext_vector_type(8)));
typedef float f32x4 __attribute__((ext_vector_type(4)));

// ---- wave-level inclusive scan (64 lanes, 6 shuffle steps, no barriers) ----
__device__ __forceinline__ int wave_iscan(int v, int lane) {
#pragma unroll
    for (int d = 1; d < 64; d <<= 1) {
        int t = __shfl_up(v, d, 64);
        if (lane >= d) v += t;
    }
    return v;
}

// ================= K1: bucket (blocks 0..585) || gemm1 (blocks 586..976) ==========
// The two roles are independent: bucket builds the edge-bucket array from
// row/col; gemm1 computes UNSCALED h1 = fp16(X @ W1) (dinv scaling lives in
// gather1's v_fma_mix, which makes gemm1 independent of place's dinv output).
// LDS is overlaid: one 16.9KB buffer, each role casts its own layout.

__device__ __forceinline__ void bucket_role(char* smem, const int* __restrict__ row,
                                            const int* __restrict__ col,
                                            int* __restrict__ gcursor,
                                            unsigned* __restrict__ bke, int E,
                                            int chunk) {
    int* hist = (int*)smem;            // [NBK]
    int* pfx = hist + NBK;             // [NBK]
    int* gbase = pfx + NBK;            // [NBK]
    int* lcnt = gbase + NBK;           // [NBK]
    unsigned* ord = (unsigned*)(lcnt + NBK);            // [CHUNK]
    unsigned char* obkt = (unsigned char*)(ord + CHUNK);  // [CHUNK]

    const int t = threadIdx.x;
    const int lane = t & 63;
    const int wid = t >> 6;
    const int e0 = chunk * CHUNK;
    const int nE = min(CHUNK, E - e0);

    for (int i = t; i < NBK; i += 256) {
        hist[i] = 0;
        lcnt[i] = 0;
    }
    __syncthreads();

    for (int i = t; i < nE; i += 256) atomicAdd(&hist[col[e0 + i] >> BSHIFT], 1);
    __syncthreads();

    // shuffle-based 256-wide inclusive scan (zeros beyond NBK don't affect t<NBK)
    int v = (t < NBK) ? hist[t] : 0;
    int incl = wave_iscan(v, lane);
    if (lane == 63) ord[wid] = (unsigned)incl;  // ord[0..3] scratch (repacked later)
    __syncthreads();
    int add = 0;
#pragma unroll
    for (int w = 0; w < 3; ++w)
        if (w < wid) add += (int)ord[w];
    incl += add;
    if (t < NBK) {
        pfx[t] = incl - v;  // exclusive
        gbase[t] = t * BCAP + ((v > 0) ? atomicAdd(&gcursor[t], v) : 0);
    }
    __syncthreads();

    for (int i = t; i < nE; i += 256) {
        int r = row[e0 + i];
        int c = col[e0 + i];
        int b = c >> BSHIFT;
        int pos = pfx[b] + atomicAdd(&lcnt[b], 1);
        ord[pos] = ((unsigned)r << BSHIFT) | (unsigned)(c & BMASK);
        obkt[pos] = (unsigned char)b;
    }
    __syncthreads();

    for (int i = t; i < nE; i += 256) {
        int b = obkt[i];
        bke[(size_t)gbase[b] + (i - pfx[b])] = ord[i];
    }
}

// gemm1: h1s[node, f] = fp16( (X @ W1)[node, f] ), row stride 64 halves. UNSCALED.
// v_mfma_f32_16x16x32_f16: A[m=lane&15][k=quad*8+j], B[k][n=lane&15],
// C: col=lane&15, row=quad*4+reg.
__device__ __forceinline__ void gemm1_role(char* smem, const float* __restrict__ X,
                                           const float* __restrict__ W,
                                           __half* __restrict__ Hs, int M, int bnode0) {
    constexpr int WPITCH = 66;
    _Float16* wh = (_Float16*)smem;  // [128 * 66]

    const int tid = threadIdx.x;

    for (int i = tid; i < N_FEAT * HIDDEN; i += 256) {
        int k = i / HIDDEN, n = i % HIDDEN;
        wh[k * WPITCH + n] = (_Float16)W[k * HIDDEN + n];
    }
    __syncthreads();

    const int wid = tid >> 6;
    const int lane = tid & 63;
    const int m = lane & 15;
    const int quad = lane >> 4;

    f16x8 bf[4][4];
#pragma unroll
    for (int kc = 0; kc < 4; ++kc)
#pragma unroll
        for (int nt = 0; nt < 4; ++nt)
#pragma unroll
            for (int j = 0; j < 8; ++j)
                bf[kc][nt][j] = wh[(kc * 32 + quad * 8 + j) * WPITCH + nt * 16 + m];

    for (int nt4 = 0; nt4 < 4; ++nt4) {
        const int nb = bnode0 + wid * 64 + nt4 * 16;
        if (nb >= M) break;
        const int rowi = min(nb + m, M - 1);
        const float* xr = X + (size_t)rowi * N_FEAT;

        f32x4 acc[4];
#pragma unroll
        for (int nt = 0; nt < 4; ++nt) acc[nt] = (f32x4){0.f, 0.f, 0.f, 0.f};

#pragma unroll
        for (int kc = 0; kc < 4; ++kc) {
            float4 u0 = *(const float4*)&xr[kc * 32 + quad * 8];
            float4 u1 = *(const float4*)&xr[kc * 32 + quad * 8 + 4];
            f16x8 af;
            af[0] = (_Float16)u0.x;
            af[1] = (_Float16)u0.y;
            af[2] = (_Float16)u0.z;
            af[3] = (_Float16)u0.w;
            af[4] = (_Float16)u1.x;
            af[5] = (_Float16)u1.y;
            af[6] = (_Float16)u1.z;
            af[7] = (_Float16)u1.w;
#pragma unroll
            for (int nt = 0; nt < 4; ++nt)
                acc[nt] = __builtin_amdgcn_mfma_f32_16x16x32_f16(af, bf[kc][nt], acc[nt], 0, 0, 0);
        }

#pragma unroll
        for (int reg = 0; reg < 4; ++reg) {
            const int node = nb + quad * 4 + reg;
            if (node < M) {
#pragma unroll
                for (int nt = 0; nt < 4; ++nt)
                    Hs[(size_t)node * HIDDEN + nt * 16 + m] = __float2half(acc[nt][reg]);
            }
        }
    }
}

__global__ __launch_bounds__(256) void k1_bucket_gemm1(const int* __restrict__ row,
                                                       const int* __restrict__ col,
                                                       int* __restrict__ gcursor,
                                                       unsigned* __restrict__ bke, int E,
                                                       const float* __restrict__ x,
                                                       const float* __restrict__ W1,
                                                       __half* __restrict__ h1s, int M) {
    __shared__ __align__(16) char smem[N_FEAT * 66 * 2];  // 16896B >= bucket's 13376B
    const int bid = blockIdx.x;
    if (bid < NCHUNKS)
        bucket_role(smem, row, col, gcursor, bke, E, bid);
    else
        gemm1_role(smem, x, W1, h1s, M, (bid - NCHUNKS) * 256);
}

// ---- fused per-bucket: bucketBase scan + hist -> rowptr + dinv -> scatter CSR ----
// Scans as wave shuffle-scans: 7 barriers total (was ~36; 196 blocks on 256 CUs
// means block latency is wall time -- barriers were pure serial cost).
// Every cross-wave scratch write is fenced by __syncthreads() before any read
// (round-8 lesson: the step-4 combine raced without it).

__global__ __launch_bounds__(256) void place_kernel(const int* __restrict__ gcursor,
                                                    const unsigned* __restrict__ bke,
                                                    int* __restrict__ rowptr,
                                                    float* __restrict__ dinv,
                                                    int* __restrict__ csr_src, int n) {
    __shared__ int hist[BUCKET_NODES];
    __shared__ int cur[BUCKET_NODES];
    __shared__ int tsum[256];

    const int b = blockIdx.x, t = threadIdx.x;
    const int lane = t & 63;
    const int wid = t >> 6;
    const int node0 = b << BSHIFT;
    const int nNodes = min(BUCKET_NODES, n - node0);

    // 1) bucket base: inclusive scan over the 196 bucket counts
    const int myCnt = (t < NBK) ? gcursor[t] : 0;
    int incl1 = wave_iscan(myCnt, lane);
    if (lane == 63) cur[wid] = incl1;  // cur[0..3] scratch
    __syncthreads();
    int add1 = 0;
#pragma unroll
    for (int w = 0; w < 3; ++w)
        if (w < wid) add1 += cur[w];
    incl1 += add1;
    tsum[t] = incl1;
    __syncthreads();
    const int base = tsum[b] - gcursor[b];  // exclusive prefix at b
    const int nb = gcursor[b];

    // 2) zero hist
    hist[t] = 0;
    hist[t + 256] = 0;
    __syncthreads();

    // 3) histogram
    const unsigned* src = bke + (size_t)b * BCAP;
    for (int i = t; i < nb; i += 256) atomicAdd(&hist[src[i] & BMASK], 1);
    __syncthreads();

    // 4) 512-wide exclusive scan via pairs: thread t owns elements 2t, 2t+1
    const int c0 = hist[2 * t];
    const int c1 = hist[2 * t + 1];
    const int s = c0 + c1;
    int incl2 = wave_iscan(s, lane);
    if (lane == 63) tsum[wid] = incl2;  // tsum scratch (base already in regs)
    __syncthreads();                    // REQUIRED: cross-wave write->read fence
    int add2 = 0;
#pragma unroll
    for (int w = 0; w < 3; ++w)
        if (w < wid) add2 += tsum[w];
    incl2 += add2;
    const int e0 = base + incl2 - s;
    const int e1 = e0 + c0;

    cur[2 * t] = e0;
    cur[2 * t + 1] = e1;
    if (2 * t < nNodes) {
        rowptr[node0 + 2 * t] = e0;
        dinv[node0 + 2 * t] = rsqrtf((float)(c0 + 1));
    }
    if (2 * t + 1 < nNodes) {
        rowptr[node0 + 2 * t + 1] = e1;
        dinv[node0 + 2 * t + 1] = rsqrtf((float)(c1 + 1));
    }
    if (t == 0 && node0 + nNodes == n) rowptr[n] = N_EDGES;
    __syncthreads();

    // 5) scatter
    for (int i = t; i < nb; i += 256) {
        unsigned p = src[i];
        int pos = atomicAdd(&cur[p & BMASK], 1);
        csr_src[pos] = (int)(p >> BSHIFT);
    }
}

// ---------------- gather accumulate primitive ----------------
// v_fma_mix_f32: acc += (float)h16 * s -- exact f16->f32 promote, f32 multiply,
// 1 instr/feature. s=1.0f for pre-scaled rows, s=dinv[r] for unscaled h1 rows.

__device__ inline void acc_mix16(float (&acc)[8], uint4 u, float s) {
    const unsigned* w = (const unsigned*)&u;
#pragma unroll
    for (int k = 0; k < 4; ++k) {
        asm("v_fma_mix_f32 %0, %1, %2, %0 op_sel:[0,0,0] op_sel_hi:[1,0,0]"
            : "+v"(acc[2 * k])
            : "v"(w[k]), "v"(s));
        asm("v_fma_mix_f32 %0, %1, %2, %0 op_sel:[1,0,0] op_sel_hi:[1,0,0]"
            : "+v"(acc[2 * k + 1])
            : "v"(w[k]), "v"(s));
    }
}

// ---------------- fused gather1 + GEMM2 ----------------
// Block = 256 threads, 64 nodes. Phase 1: each wave handles 8 nodes/round x 2
// rounds; group g (8 lanes) owns one node, lane q one 16B chunk; aggregate
// UNSCALED h1s rows with per-edge weight dinv[r] (self weight dinv[c]) via
// v_fma_mix, plain 4-deep edge unroll (the r6-proven loop shape). Apply
// dinv[c]/b1/relu, store fp16 row to LDS. Phase 2: 64x64x40 MFMA tile from LDS,
// epilogue writes SPLIT h2: classes 0-31 -> h2a (64B rows = 1 line/edge-read),
// 32-39 -> h2b (16B rows, 1.6MB L2-resident).
// out = dinv_c * sum_r(dinv_r * h_r) + b.

__global__ __launch_bounds__(256) void gather1_gemm2_kernel(
    const int* __restrict__ rowptr, const int* __restrict__ csr_src,
    const float* __restrict__ dinv, const __half* __restrict__ h1s,
    const float* __restrict__ b1, const float* __restrict__ W2,
    __half* __restrict__ h2a, __half* __restrict__ h2b, int n) {
    constexpr int APITCH = 72;  // halves; 144B rows keep 16B alignment for b128 LDS ops
    constexpr int WPITCH = 50;

    __shared__ _Float16 agg[64 * APITCH];
    __shared__ _Float16 wh[64 * WPITCH];
    __shared__ float sdinv[64];

    const int tid = threadIdx.x;
    const int base = blockIdx.x * 64;

    // stage W2 (64x40, zero-padded to 48 cols) and this block's dinv
    for (int i = tid; i < 64 * 48; i += 256) {
        int k = i / 48, nn = i % 48;
        wh[k * WPITCH + nn] = (nn < 40) ? (_Float16)W2[k * 40 + nn] : (_Float16)0.0f;
    }
    if (tid < 64) {
        int node = base + tid;
        sdinv[tid] = (node < n) ? dinv[node] : 0.f;
    }
    __syncthreads();

    const int wid = tid >> 6;
    const int lane = tid & 63;
    const int g = lane >> 3;  // node slot within wave
    const int q = lane & 7;   // 16B chunk within 128B row
    const __half* hq = h1s + q * 8;

    // ---- phase 1: gather 64 nodes into LDS (2 rounds of 8 nodes/wave) ----
#pragma unroll
    for (int t = 0; t < 2; ++t) {
        const int nl = t * 32 + wid * 8 + g;
        const int c = base + nl;
        if (c < n) {
            float acc[8];
#pragma unroll
            for (int j = 0; j < 8; ++j) acc[j] = 0.f;

            const float dc = sdinv[nl];
            // self loop, weight dinv[c]
            acc_mix16(acc, *(const uint4*)(hq + (size_t)c * HIDDEN), dc);

            int e = rowptr[c];
            const int eEnd = rowptr[c + 1];
            for (; e + 4 <= eEnd; e += 4) {
                int r0 = csr_src[e];
                int r1 = csr_src[e + 1];
                int r2 = csr_src[e + 2];
                int r3 = csr_src[e + 3];
                float s0 = dinv[r0];
                float s1 = dinv[r1];
                float s2 = dinv[r2];
                float s3 = dinv[r3];
                uint4 u0 = *(const uint4*)(hq + (size_t)r0 * HIDDEN);
                uint4 u1 = *(const uint4*)(hq + (size_t)r1 * HIDDEN);
                uint4 u2 = *(const uint4*)(hq + (size_t)r2 * HIDDEN);
                uint4 u3 = *(const uint4*)(hq + (size_t)r3 * HIDDEN);
                acc_mix16(acc, u0, s0);
                acc_mix16(acc, u1, s1);
                acc_mix16(acc, u2, s2);
                acc_mix16(acc, u3, s3);
            }
            if (e + 2 <= eEnd) {
                int t0 = csr_src[e];
                int t1 = csr_src[e + 1];
                float s0 = dinv[t0];
                float s1 = dinv[t1];
                uint4 u0 = *(const uint4*)(hq + (size_t)t0 * HIDDEN);
                uint4 u1 = *(const uint4*)(hq + (size_t)t1 * HIDDEN);
                acc_mix16(acc, u0, s0);
                acc_mix16(acc, u1, s1);
                e += 2;
            }
            if (e < eEnd) {
                int r = csr_src[e];
                acc_mix16(acc, *(const uint4*)(hq + (size_t)r * HIDDEN), dinv[r]);
            }

            _Float16 hv[8];
#pragma unroll
            for (int j = 0; j < 8; ++j) {
                float v = fmaf(acc[j], dc, b1[q * 8 + j]);
                hv[j] = (_Float16)fmaxf(v, 0.f);
            }
            *(f16x8*)&agg[nl * APITCH + q * 8] = *(f16x8*)hv;
        }
    }
    __syncthreads();

    // ---- phase 2: GEMM2 on the 64 LDS rows ----
    const int m = lane & 15;
    const int quad = lane >> 4;

    f16x8 bf[2][3];
#pragma unroll
    for (int kc = 0; kc < 2; ++kc)
#pragma unroll
        for (int nt = 0; nt < 3; ++nt)
#pragma unroll
            for (int j = 0; j < 8; ++j)
                bf[kc][nt][j] = wh[(kc * 32 + quad * 8 + j) * WPITCH + nt * 16 + m];

    const int nl0 = wid * 16;  // this wave's 16-node tile

    f32x4 acc2[3];
#pragma unroll
    for (int nt = 0; nt < 3; ++nt) acc2[nt] = (f32x4){0.f, 0.f, 0.f, 0.f};

#pragma unroll
    for (int kc = 0; kc < 2; ++kc) {
        f16x8 af = *(const f16x8*)&agg[(nl0 + m) * APITCH + kc * 32 + quad * 8];
#pragma unroll
        for (int nt = 0; nt < 3; ++nt)
            acc2[nt] = __builtin_amdgcn_mfma_f32_16x16x32_f16(af, bf[kc][nt], acc2[nt], 0, 0, 0);
    }

#pragma unroll
    for (int reg = 0; reg < 4; ++reg) {
        const int nl = nl0 + quad * 4 + reg;
        const int node = base + nl;
        if (node < n) {
            const float s = sdinv[nl];
#pragma unroll
            for (int nt = 0; nt < 3; ++nt) {
                const int f = nt * 16 + m;
                const __half hv = __float2half(acc2[nt][reg] * s);
                if (f < 32)
                    h2a[(size_t)node * 32 + f] = hv;
                else if (f < N_CLASSES)
                    h2b[(size_t)node * 8 + (f - 32)] = hv;
            }
        }
    }
}

// ---------------- layer-2 gather: 12 nodes x 5 chunks, split h2a/h2b ----------------
// Contiguous node blocks (R2 showed locality >> balance). q<4 lanes read 16B
// chunks of h2a (stride 32 halves, 1 line/row); q==4 reads h2b (stride 8,
// L2-resident). h2 rows are pre-scaled by dinv_r -> weight-1 accumulate.
// 8-deep edge unroll (deeper MLP; this kernel has VGPR headroom, no LDS).

__global__ __launch_bounds__(256) void gather2_kernel(const int* __restrict__ rowptr,
                                                      const int* __restrict__ csr_src,
                                                      const float* __restrict__ dinv,
                                                      const __half* __restrict__ h2a,
                                                      const __half* __restrict__ h2b,
                                                      const float* __restrict__ bias,
                                                      float* __restrict__ out, int n) {
    const int wave = (blockIdx.x * blockDim.x + threadIdx.x) >> 6;
    const int lane = threadIdx.x & 63;
    if (lane >= 60) return;
    const int g = lane / 5;  // node slot within wave
    const int q = lane % 5;  // feature chunk
    const int c = wave * 12 + g;
    if (c >= n) return;

    const float one = 1.0f;
    const __half* hq = (q < 4) ? (h2a + q * 8) : h2b;
    const int sh = (q < 4) ? 5 : 3;  // log2(row stride in halves)

    const int eBeg = rowptr[c];
    const int eEnd = rowptr[c + 1];

    float acc[8];
#pragma unroll
    for (int j = 0; j < 8; ++j) acc[j] = 0.f;

    // self loop
    acc_mix16(acc, *(const uint4*)(hq + ((size_t)c << sh)), one);

    int e = eBeg;
    for (; e + 8 <= eEnd; e += 8) {
        int r[8];
#pragma unroll
        for (int k = 0; k < 8; ++k) r[k] = csr_src[e + k];
        uint4 u[8];
#pragma unroll
        for (int k = 0; k < 8; ++k) u[k] = *(const uint4*)(hq + ((size_t)r[k] << sh));
#pragma unroll
        for (int k = 0; k < 8; ++k) acc_mix16(acc, u[k], one);
    }
    if (e + 4 <= eEnd) {
        int r0 = csr_src[e];
        int r1 = csr_src[e + 1];
        int r2 = csr_src[e + 2];
        int r3 = csr_src[e + 3];
        uint4 u0 = *(const uint4*)(hq + ((size_t)r0 << sh));
        uint4 u1 = *(const uint4*)(hq + ((size_t)r1 << sh));
        uint4 u2 = *(const uint4*)(hq + ((size_t)r2 << sh));
        uint4 u3 = *(const uint4*)(hq + ((size_t)r3 << sh));
        acc_mix16(acc, u0, one);
        acc_mix16(acc, u1, one);
        acc_mix16(acc, u2, one);
        acc_mix16(acc, u3, one);
        e += 4;
    }
    if (e + 2 <= eEnd) {
        int r0 = csr_src[e];
        int r1 = csr_src[e + 1];
        uint4 u0 = *(const uint4*)(hq + ((size_t)r0 << sh));
        uint4 u1 = *(const uint4*)(hq + ((size_t)r1 << sh));
        acc_mix16(acc, u0, one);
        acc_mix16(acc, u1, one);
        e += 2;
    }
    if (e < eEnd) {
        int r = csr_src[e];
        acc_mix16(acc, *(const uint4*)(hq + ((size_t)r << sh)), one);
    }

    const float dc = dinv[c];
    float o[8];
#pragma unroll
    for (int j = 0; j < 8; ++j) {
        float v = fmaf(acc[j], dc, bias[q * 8 + j]);
        o[j] = v;
    }

    float* dst = &out[(size_t)c * N_CLASSES + q * 8];
    *(float4*)dst = make_float4(o[0], o[1], o[2], o[3]);
    *(float4*)(dst + 4) = make_float4(o[4], o[5], o[6], o[7]);
}

// ---------------- launch ----------------

extern "C" void kernel_launch(void* const* d_in, const int* in_sizes, int n_in,
                              void* d_out, int out_size, void* d_ws, size_t ws_size,
                              hipStream_t stream) {
    const float* x = (const float*)d_in[0];
    const int* row = (const int*)d_in[1];
    const int* col = row + N_EDGES;
    const float* W1 = (const float*)d_in[2];
    const float* b1 = (const float*)d_in[3];
    const float* W2 = (const float*)d_in[4];
    const float* b2 = (const float*)d_in[5];
    float* out = (float*)d_out;

    const int N = N_NODES, E = N_EDGES;

    // 256B-aligned workspace carve-up: h1s rows 128B-aligned (2 lines/row),
    // h2a rows 64B-aligned (exactly 1 line/row), h2b 16B rows.
    char* p = (char*)d_ws;
    auto alloc = [&](size_t bytes) {
        char* q = p;
        p += (bytes + 255) & ~(size_t)255;
        return q;
    };
    int* rowptr = (int*)alloc((size_t)(N + 1) * 4);
    int* csr_src = (int*)alloc((size_t)E * 4);
    int* gcursor = (int*)alloc((size_t)NBK * 4);
    unsigned* bke = (unsigned*)alloc((size_t)NBK * BCAP * 4);
    float* dinv = (float*)alloc((size_t)N * 4);
    __half* h1s = (__half*)alloc((size_t)N * HIDDEN * 2);  // stride 64 halves (128B)
    __half* h2a = (__half*)alloc((size_t)N * 32 * 2);      // classes 0-31, 64B rows
    __half* h2b = (__half*)alloc((size_t)N * 8 * 2);       // classes 32-39, 16B rows

    hipMemsetAsync(gcursor, 0, (size_t)NBK * 4, stream);

    // K1: bucket (586 blocks) || gemm1 unscaled (391 blocks) -- independent roles
    k1_bucket_gemm1<<<NCHUNKS + NT1, 256, 0, stream>>>(row, col, gcursor, bke, E,
                                                       x, W1, h1s, N);

    // place: bke -> rowptr/dinv/csr_src
    place_kernel<<<NBK, 256, 0, stream>>>(gcursor, bke, rowptr, dinv, csr_src, N);

    // fused: gather layer-1 (per-edge dinv weight, relu, b1) -> LDS -> GEMM2 -> h2a/h2b
    gather1_gemm2_kernel<<<(N + 63) / 64, 256, 0, stream>>>(rowptr, csr_src, dinv, h1s,
                                                            b1, W2, h2a, h2b, N);

    // layer-2 gather: 12 nodes x 5 chunks = 60/64 lanes, contiguous nodes
    gather2_kernel<<<(N + 47) / 48, 256, 0, stream>>>(rowptr, csr_src, dinv, h2a, h2b,
                                                      b2, out, N);
}